// Round 10
// baseline (8116.622 us; speedup 1.0000x reference)
//
#include <hip/hip_runtime.h>
#include <cstdint>
#include <cstddef>

#define NN 2048
#define NB 8
#define F0C 256
#define F1C 128
#define F2C 512

typedef double f64x4 __attribute__((ext_vector_type(4)));

// ---------------- helpers ----------------
__device__ __forceinline__ double waveSumD(double v) {
#pragma unroll
    for (int o = 32; o; o >>= 1) v += __shfl_down(v, o, 64);
    return v;
}

// ---------------- deg[row] = f64 rowsum of adj row ----------------
__global__ __launch_bounds__(256) void deg_k(const float* __restrict__ adj,
                                             double* __restrict__ degD) {
    const size_t row = blockIdx.x;
    const float4* r4 = (const float4*)(adj + row * (size_t)NN);
    float4 a = r4[threadIdx.x];
    float4 b = r4[threadIdx.x + 256];
    double s = (((double)a.x + a.y) + ((double)a.z + a.w)) +
               (((double)b.x + b.y) + ((double)b.z + b.w));
    s = waveSumD(s);
    __shared__ double red[4];
    if (!(threadIdx.x & 63)) red[threadIdx.x >> 6] = s;
    __syncthreads();
    if (!threadIdx.x) degD[row] = (red[0] + red[1]) + (red[2] + red[3]);
}

// ---------------- f64 MFMA GEMM, double-buffered (mode-3 mapping, HW-verified r8) --
// v_mfma_f64_16x16x4f64 fragment mapping (probe mode=3):
//   A: lane l holds A[row=l&15][k=l>>4]
//   B: lane l holds B[k=l>>4][col=l&15]
//   D: lane l, reg v holds D[row=(l>>4)+4*v][col=l&15]
// C[b] = Ahat[b] @ B[b];  ADD_AT: Ahat = (double)A + (double)A^T (at frag build).
// EPI: 0 = store (CT cast), 2 = prox update + softshrink (deg from degD).
// Block 256 thr = 4 waves (2x2), wave tile 64x64 (4x4 frags), tile 128x128, BK=16.
// Pipeline: LOAD(k+1)->regs | COMPUTE(buf[k&1]) | STORE(buf[k^1]) | barrier.
// Single barrier per k-step is sufficient with 2 buffers: any wave at STORE has
// passed the prior barrier, hence all waves finished the compute that last read
// the buffer being overwritten.
template <typename BT, typename CT, bool ADD_AT, int EPI>
__global__ __launch_bounds__(256, 2) void mf_k(
    const float* __restrict__ A, size_t Abatch, int lda,
    const BT* __restrict__ Bm, size_t Bbatch, int ldb,
    CT* __restrict__ Cout, size_t Cbatch, int K, int Ccols,
    const float* __restrict__ S0, size_t Sbatch,
    const double* __restrict__ degD) {
    __shared__ float As[2][128][20];                  // [buf][i][k]
    __shared__ float AsT[2][ADD_AT ? 16 : 1][136];    // [buf][k][i]
    __shared__ BT Bs[2][16][132];                     // [buf][k][j]
    __shared__ double degL[EPI == 2 ? 128 : 1];

    const int b = blockIdx.z;
    const int i0 = blockIdx.x * 128;
    const int j0 = blockIdx.y * 128;
    const float* Ab = A + Abatch * (size_t)b;
    const BT* Bb = Bm + Bbatch * (size_t)b;
    const int t = threadIdx.x;
    const int l = t & 63;
    const int wv = t >> 6;
    const int wr = (wv >> 1) * 64;   // wave row base in tile
    const int wc = (wv & 1) * 64;    // wave col base in tile
    const int lr = l & 15;           // A-row / B-col / D-col lane index
    const int lk = l >> 4;           // k lane index (0..3); D rows = lk + 4v

    // staging indices (per thread)
    const int sa_i = t >> 2, sa_q = (t & 3) * 4;          // A: row, col quad
    const int st_k = t >> 4, st_c = (t & 15) * 4;         // AT/B upper half? no:
    const int sb_k = t >> 5, sb_c = (t & 31) * 4;         // AT/B: row, col quad

    // staging registers
    float4 aR[2];
    float4 atR[2];
    double2 bRd[2][2];
    float4 bRf[2];

    auto LOAD = [&](int k0) {
#pragma unroll
        for (int r2 = 0; r2 < 2; ++r2) {
            const int i = sa_i + 64 * r2;
            aR[r2] = *(const float4*)(Ab + (size_t)(i0 + i) * lda + k0 + sa_q);
        }
        if (ADD_AT) {
#pragma unroll
            for (int r2 = 0; r2 < 2; ++r2) {
                const int k = sb_k + 8 * r2;
                atR[r2] = *(const float4*)(Ab + (size_t)(k0 + k) * lda + i0 + sb_c);
            }
        }
        if constexpr (sizeof(BT) == 8) {
#pragma unroll
            for (int r2 = 0; r2 < 2; ++r2) {
                const int k = sb_k + 8 * r2;
                const BT* src = Bb + (size_t)(k0 + k) * ldb + j0 + sb_c;
                bRd[r2][0] = *(const double2*)src;
                bRd[r2][1] = *(const double2*)(src + 2);
            }
        } else {
#pragma unroll
            for (int r2 = 0; r2 < 2; ++r2) {
                const int k = sb_k + 8 * r2;
                bRf[r2] = *(const float4*)(Bb + (size_t)(k0 + k) * ldb + j0 + sb_c);
            }
        }
    };

    auto STORE = [&](int bf) {
#pragma unroll
        for (int r2 = 0; r2 < 2; ++r2) {
            const int i = sa_i + 64 * r2;
            *(float4*)&As[bf][i][sa_q] = aR[r2];
        }
        if (ADD_AT) {
#pragma unroll
            for (int r2 = 0; r2 < 2; ++r2) {
                const int k = sb_k + 8 * r2;
                *(float4*)&AsT[bf][k][sb_c] = atR[r2];
            }
        }
        if constexpr (sizeof(BT) == 8) {
#pragma unroll
            for (int r2 = 0; r2 < 2; ++r2) {
                const int k = sb_k + 8 * r2;
                *(double2*)&Bs[bf][k][sb_c] = bRd[r2][0];
                *(double2*)&Bs[bf][k][sb_c + 2] = bRd[r2][1];
            }
        } else {
#pragma unroll
            for (int r2 = 0; r2 < 2; ++r2) {
                const int k = sb_k + 8 * r2;
                *(float4*)&Bs[bf][k][sb_c] = bRf[r2];
            }
        }
    };

    f64x4 acc[4][4];
#pragma unroll
    for (int r = 0; r < 4; ++r)
#pragma unroll
        for (int c = 0; c < 4; ++c)
#pragma unroll
            for (int v = 0; v < 4; ++v) acc[r][c][v] = 0.0;

    if (EPI == 2) {
        if (t < 128) degL[t] = degD[(size_t)b * NN + i0 + t];
    }

    const int nk = K / 16;
    LOAD(0);
    STORE(0);
    __syncthreads();

    for (int ks = 0; ks < nk; ++ks) {
        const int cur = ks & 1;
        if (ks + 1 < nk) LOAD((ks + 1) * 16);
        // compute from buf[cur]
#pragma unroll
        for (int kk = 0; kk < 4; ++kk) {
            const int kr = kk * 4 + lk;
            double av[4], bv[4];
#pragma unroll
            for (int r = 0; r < 4; ++r) {
                const int ii = wr + r * 16 + lr;
                double a = (double)As[cur][ii][kr];
                if (ADD_AT) a += (double)AsT[cur][kr][ii];
                av[r] = a;
            }
#pragma unroll
            for (int c = 0; c < 4; ++c)
                bv[c] = (double)Bs[cur][kr][wc + c * 16 + lr];
#pragma unroll
            for (int r = 0; r < 4; ++r)
#pragma unroll
                for (int c = 0; c < 4; ++c)
                    acc[r][c] = __builtin_amdgcn_mfma_f64_16x16x4f64(
                        av[r], bv[c], acc[r][c], 0, 0, 0);
        }
        if (ks + 1 < nk) {
            STORE(cur ^ 1);
            __syncthreads();
        }
    }

    // epilogue (D: row = lk + 4v, col = lr)
#pragma unroll
    for (int r = 0; r < 4; ++r) {
#pragma unroll
        for (int v = 0; v < 4; ++v) {
            const int rl = wr + r * 16 + lk + 4 * v;
            const size_t grow = (size_t)(i0 + rl);
            double cA = 0.0;
            if (EPI == 2) cA = 0.8 - 0.02 * degL[rl];
#pragma unroll
            for (int c = 0; c < 4; ++c) {
                const int gcol = j0 + wc + c * 16 + lr;
                double y = acc[r][c][v];
                if (EPI == 2) {
                    const double sv = (double)Bb[grow * (size_t)ldb + gcol];
                    const double s0v =
                        (double)S0[Sbatch * (size_t)b + grow * (size_t)Ccols + gcol];
                    const double u = cA * sv + 0.01 * y + 0.2 * s0v;
                    y = (u > 0.1) ? (u - 0.1) : ((u < -0.1) ? (u + 0.1) : 0.0);
                }
                Cout[Cbatch * (size_t)b + grow * (size_t)Ccols + gcol] = (CT)y;
            }
        }
    }
}

// ---------------- fp64-accumulating VALU GEMM (round-5 verbatim; weight GEMMs) ----
template <typename BT, typename CT>
__global__ __launch_bounds__(256) void gemm64_k(
    const float* __restrict__ A, size_t Abatch, int lda,
    const BT* __restrict__ Bm, size_t Bbatch, int ldb,
    CT* __restrict__ Cout, size_t Cbatch,
    int K, int Ccols,
    const float* __restrict__ bias,
    const float* __restrict__ S0, size_t Sbatch,
    int addAT, int btrans, int epi) {
    __shared__ float As[32][132];
    __shared__ float AsT[32][132];
    __shared__ BT Bs[32][68];
    __shared__ double degLDS[2][128];
    const int b = blockIdx.z;
    const int i0 = blockIdx.x * 128;
    const int j0 = blockIdx.y * 64;
    const float* Ab = A + Abatch * (size_t)b;
    const BT* Bb = Bm + Bbatch * (size_t)b;
    const int t = threadIdx.x;
    const int wv = t >> 6, ln = t & 63;
    const int ri = (wv >> 1) * 64 + (ln >> 3) * 8;
    const int rj = ((wv & 1) * 8 + (ln & 7)) * 4;

    double acc[8][4];
#pragma unroll
    for (int i = 0; i < 8; ++i)
#pragma unroll
        for (int j = 0; j < 4; ++j) acc[i][j] = 0.0;

    const int a_i = t >> 1, a_m = (t & 1) * 16;
    const int p_m = t >> 3, p_i = (t & 7) * 16;
    const int b_m = t >> 3, b_j = (t & 7) * 8;
    const int w_j = t >> 2, w_m = (t & 3) * 8;
    double degacc = 0.0;

    for (int k0 = 0; k0 < K; k0 += 32) {
        if (k0) __syncthreads();
        {
            const float4* src =
                (const float4*)(Ab + (size_t)(i0 + a_i) * lda + k0 + a_m);
            float4 v0 = src[0], v1 = src[1], v2 = src[2], v3 = src[3];
            if (epi == 2)
                degacc += (((double)v0.x + v0.y) + ((double)v0.z + v0.w)) +
                          (((double)v1.x + v1.y) + ((double)v1.z + v1.w)) +
                          (((double)v2.x + v2.y) + ((double)v2.z + v2.w)) +
                          (((double)v3.x + v3.y) + ((double)v3.z + v3.w));
            As[a_m + 0][a_i] = v0.x;  As[a_m + 1][a_i] = v0.y;
            As[a_m + 2][a_i] = v0.z;  As[a_m + 3][a_i] = v0.w;
            As[a_m + 4][a_i] = v1.x;  As[a_m + 5][a_i] = v1.y;
            As[a_m + 6][a_i] = v1.z;  As[a_m + 7][a_i] = v1.w;
            As[a_m + 8][a_i] = v2.x;  As[a_m + 9][a_i] = v2.y;
            As[a_m + 10][a_i] = v2.z; As[a_m + 11][a_i] = v2.w;
            As[a_m + 12][a_i] = v3.x; As[a_m + 13][a_i] = v3.y;
            As[a_m + 14][a_i] = v3.z; As[a_m + 15][a_i] = v3.w;
        }
        if (addAT) {
            const float4* src =
                (const float4*)(Ab + (size_t)(k0 + p_m) * lda + i0 + p_i);
            float4 v0 = src[0], v1 = src[1], v2 = src[2], v3 = src[3];
            AsT[p_m][p_i + 0] = v0.x;  AsT[p_m][p_i + 1] = v0.y;
            AsT[p_m][p_i + 2] = v0.z;  AsT[p_m][p_i + 3] = v0.w;
            AsT[p_m][p_i + 4] = v1.x;  AsT[p_m][p_i + 5] = v1.y;
            AsT[p_m][p_i + 6] = v1.z;  AsT[p_m][p_i + 7] = v1.w;
            AsT[p_m][p_i + 8] = v2.x;  AsT[p_m][p_i + 9] = v2.y;
            AsT[p_m][p_i + 10] = v2.z; AsT[p_m][p_i + 11] = v2.w;
            AsT[p_m][p_i + 12] = v3.x; AsT[p_m][p_i + 13] = v3.y;
            AsT[p_m][p_i + 14] = v3.z; AsT[p_m][p_i + 15] = v3.w;
        }
        if (!btrans) {
            const BT* src = Bb + (size_t)(k0 + b_m) * ldb + j0 + b_j;
            if constexpr (sizeof(BT) == 8) {
                const double2* s2 = (const double2*)src;
                double2 u0 = s2[0], u1 = s2[1], u2 = s2[2], u3 = s2[3];
                Bs[b_m][b_j + 0] = (BT)u0.x; Bs[b_m][b_j + 1] = (BT)u0.y;
                Bs[b_m][b_j + 2] = (BT)u1.x; Bs[b_m][b_j + 3] = (BT)u1.y;
                Bs[b_m][b_j + 4] = (BT)u2.x; Bs[b_m][b_j + 5] = (BT)u2.y;
                Bs[b_m][b_j + 6] = (BT)u3.x; Bs[b_m][b_j + 7] = (BT)u3.y;
            } else {
                const float4* s4 = (const float4*)src;
                float4 u0 = s4[0], u1 = s4[1];
                Bs[b_m][b_j + 0] = (BT)u0.x; Bs[b_m][b_j + 1] = (BT)u0.y;
                Bs[b_m][b_j + 2] = (BT)u0.z; Bs[b_m][b_j + 3] = (BT)u0.w;
                Bs[b_m][b_j + 4] = (BT)u1.x; Bs[b_m][b_j + 5] = (BT)u1.y;
                Bs[b_m][b_j + 6] = (BT)u1.z; Bs[b_m][b_j + 7] = (BT)u1.w;
            }
        } else {
            const float* Wf = reinterpret_cast<const float*>(Bm);
            const float4* src =
                (const float4*)(Wf + (size_t)(j0 + w_j) * ldb + k0 + w_m);
            float4 v0 = src[0], v1 = src[1];
            Bs[w_m + 0][w_j] = (BT)v0.x; Bs[w_m + 1][w_j] = (BT)v0.y;
            Bs[w_m + 2][w_j] = (BT)v0.z; Bs[w_m + 3][w_j] = (BT)v0.w;
            Bs[w_m + 4][w_j] = (BT)v1.x; Bs[w_m + 5][w_j] = (BT)v1.y;
            Bs[w_m + 6][w_j] = (BT)v1.z; Bs[w_m + 7][w_j] = (BT)v1.w;
        }
        __syncthreads();
#pragma unroll 4
        for (int mk = 0; mk < 32; ++mk) {
            float4 a0 = *(const float4*)&As[mk][ri];
            float4 a1 = *(const float4*)&As[mk][ri + 4];
            double ad[8] = {a0.x, a0.y, a0.z, a0.w, a1.x, a1.y, a1.z, a1.w};
            if (addAT) {
                float4 t0 = *(const float4*)&AsT[mk][ri];
                float4 t1 = *(const float4*)&AsT[mk][ri + 4];
                ad[0] += t0.x; ad[1] += t0.y; ad[2] += t0.z; ad[3] += t0.w;
                ad[4] += t1.x; ad[5] += t1.y; ad[6] += t1.z; ad[7] += t1.w;
            }
            double bd[4];
#pragma unroll
            for (int c = 0; c < 4; ++c) bd[c] = (double)Bs[mk][rj + c];
#pragma unroll
            for (int iy = 0; iy < 8; ++iy)
#pragma unroll
                for (int jx = 0; jx < 4; ++jx)
                    acc[iy][jx] = fma(ad[iy], bd[jx], acc[iy][jx]);
        }
    }

    if (epi == 2) degLDS[t & 1][t >> 1] = degacc;
    __syncthreads();

#pragma unroll
    for (int iy = 0; iy < 8; ++iy) {
        const int row = i0 + ri + iy;
        CT* cp = Cout + Cbatch * (size_t)b + (size_t)row * Ccols + j0 + rj;
        CT o[4];
        if (epi == 0) {
#pragma unroll
            for (int jx = 0; jx < 4; ++jx) o[jx] = (CT)acc[iy][jx];
        } else if (epi == 1) {
#pragma unroll
            for (int jx = 0; jx < 4; ++jx)
                o[jx] = (CT)(acc[iy][jx] + (double)bias[j0 + rj + jx]);
        } else {
            const double dg = degLDS[0][ri + iy] + degLDS[1][ri + iy];
            const double cA = 0.8 - 0.02 * dg;
            const BT* sp = Bb + (size_t)row * ldb + j0 + rj;
            const float* s0p = S0 + Sbatch * (size_t)b + (size_t)row * Ccols + j0 + rj;
#pragma unroll
            for (int jx = 0; jx < 4; ++jx) {
                const double u = cA * (double)sp[jx] + 0.01 * acc[iy][jx] +
                                 0.2 * (double)s0p[jx];
                const double v = (u > 0.1) ? (u - 0.1) : ((u < -0.1) ? (u + 0.1) : 0.0);
                o[jx] = (CT)v;
            }
        }
        if constexpr (sizeof(CT) == 8) {
            double2 q0, q1;
            q0.x = o[0]; q0.y = o[1]; q1.x = o[2]; q1.y = o[3];
            *(double2*)cp = q0;
            *(double2*)(cp + 2) = q1;
        } else {
            *(float4*)cp = make_float4(o[0], o[1], o[2], o[3]);
        }
    }
}

// ---------------- row L2-normalize + relu ----------------
__global__ __launch_bounds__(64) void l2relu_k(float* __restrict__ buf, int F) {
    const size_t row = blockIdx.x;
    float* p = buf + row * (size_t)F;
    double ss = 0.0;
    for (int k = threadIdx.x; k < F; k += 64) {
        const double v = (double)p[k];
        ss += v * v;
    }
#pragma unroll
    for (int o = 32; o; o >>= 1) ss += __shfl_xor(ss, o, 64);
    const double den = fmax(sqrt(ss), 1e-12);
    for (int k = threadIdx.x; k < F; k += 64) {
        const double v = (double)p[k] / den;
        p[k] = (float)(v > 0.0 ? v : 0.0);
    }
}

// ---------------- BatchNorm per node, f64 two-pass ----------------
__global__ __launch_bounds__(256) void bn_k(float* __restrict__ buf,
                                            const float* __restrict__ g,
                                            const float* __restrict__ be, int fl) {
    const int n = blockIdx.x;
    const int F = 1 << fl;
    const int total = NB << fl;
    __shared__ double red[4];
    __shared__ double sh_m, sh_scale, sh_be;
    const int wv = threadIdx.x >> 6, ln = threadIdx.x & 63;
    double s = 0.0;
    for (int idx = threadIdx.x; idx < total; idx += 256) {
        const int bb = idx >> fl, f = idx & (F - 1);
        s += (double)buf[((size_t)bb * NN + n) * F + f];
    }
    s = waveSumD(s);
    if (!ln) red[wv] = s;
    __syncthreads();
    if (!threadIdx.x) sh_m = ((red[0] + red[1]) + (red[2] + red[3])) / (double)total;
    __syncthreads();
    const double m = sh_m;
    double v2 = 0.0;
    for (int idx = threadIdx.x; idx < total; idx += 256) {
        const int bb = idx >> fl, f = idx & (F - 1);
        const double d = (double)buf[((size_t)bb * NN + n) * F + f] - m;
        v2 += d * d;
    }
    v2 = waveSumD(v2);
    __syncthreads();
    if (!ln) red[wv] = v2;
    __syncthreads();
    if (!threadIdx.x) {
        const double var = ((red[0] + red[1]) + (red[2] + red[3])) / (double)total;
        sh_scale = (1.0 / sqrt(var + 1e-5)) * (double)g[n];
        sh_be = (double)be[n];
    }
    __syncthreads();
    const double sc = sh_scale, bb2 = sh_be;
    for (int idx = threadIdx.x; idx < total; idx += 256) {
        const int bb = idx >> fl, f = idx & (F - 1);
        float* pp = &buf[((size_t)bb * NN + n) * F + f];
        *pp = (float)(((double)*pp - m) * sc + bb2);
    }
}

// ---------------- softmax over last dim (512) ----------------
template <typename T>
__global__ __launch_bounds__(256) void softmax_k(const T* __restrict__ in,
                                                 float* __restrict__ out) {
    const size_t row = blockIdx.x;
    const T* p = in + row * (size_t)F2C;
    float* q = out + row * (size_t)F2C;
    const int t = threadIdx.x;
    const int wv = t >> 6, ln = t & 63;
    const double v0 = (double)p[t], v1 = (double)p[t + 256];
    double m = fmax(v0, v1);
#pragma unroll
    for (int o = 32; o; o >>= 1) m = fmax(m, __shfl_xor(m, o, 64));
    __shared__ double red[4];
    if (!ln) red[wv] = m;
    __syncthreads();
    m = fmax(fmax(red[0], red[1]), fmax(red[2], red[3]));
    const double e0 = exp(v0 - m), e1 = exp(v1 - m);
    double s = e0 + e1;
#pragma unroll
    for (int o = 32; o; o >>= 1) s += __shfl_xor(s, o, 64);
    __syncthreads();
    if (!ln) red[wv] = s;
    __syncthreads();
    s = (red[0] + red[1]) + (red[2] + red[3]);
    q[t] = (float)(e0 / s);
    q[t + 256] = (float)(e1 / s);
}

extern "C" void kernel_launch(void* const* d_in, const int* in_sizes, int n_in,
                              void* d_out, int out_size, void* d_ws, size_t ws_size,
                              hipStream_t stream) {
    const float* x = (const float*)d_in[0];
    const float* adj = (const float*)d_in[1];
    const float* W1 = (const float*)d_in[2];
    const float* b1 = (const float*)d_in[3];
    const float* g1 = (const float*)d_in[4];
    const float* be1 = (const float*)d_in[5];
    const float* W2 = (const float*)d_in[6];
    const float* b2 = (const float*)d_in[7];
    const float* g2 = (const float*)d_in[8];
    const float* be2 = (const float*)d_in[9];
    float* out = (float*)d_out;
    float* ws = (float*)d_ws;

    const size_t M2 = (size_t)NB * NN * F2C;     // 8,388,608 floats
    const size_t szAgg = (size_t)NB * NN * F0C;  // 4,194,304 floats

    const int tier = (ws_size >= ((size_t)192 << 20)) ? 0
                   : (ws_size >= ((size_t)64 << 20)) ? 1 : 2;

    if (tier == 0) {
        // [s0F 32MiB][tmpF 32MiB][D1 64MiB][D2 64MiB]; degD in dead tmpF hole.
        float* s0F = ws;
        float* tmpF = ws + M2;
        double* D1 = (double*)(ws + 2 * M2);
        double* D2 = D1 + M2;
        float* aggF = tmpF;                          // 16 MiB
        float* t1F = tmpF + szAgg;                   // 8 MiB at +16 MiB
        float* h2F = tmpF;                           // reuses agg (dead)
        double* degD = (double*)(tmpF + 7340032);    // +28 MiB, 128 KiB

        deg_k<<<NB * NN, 256, 0, stream>>>(adj, degD);
        // 1. agg = adj @ x  (MFMA)
        mf_k<float, float, false, 0><<<dim3(16, 2, 8), 256, 0, stream>>>(
            adj, (size_t)NN * NN, NN, x, (size_t)NN * F0C, F0C,
            aggF, (size_t)NN * F0C, NN, F0C, nullptr, 0, nullptr);
        // 2. t1 = agg @ W1^T + b1  (VALU, proven)
        gemm64_k<float, float><<<dim3(128, 2, 1), 256, 0, stream>>>(
            aggF, 0, F0C, W1, 0, F0C, t1F, 0, F0C, F1C, b1, nullptr, 0, 0, 1, 1);
        l2relu_k<<<NB * NN, 64, 0, stream>>>(t1F, F1C);
        bn_k<<<NN, 256, 0, stream>>>(t1F, g1, be1, 7);
        // 3. h2 = adj @ t1  (MFMA)
        mf_k<float, float, false, 0><<<dim3(16, 1, 8), 256, 0, stream>>>(
            adj, (size_t)NN * NN, NN, t1F, (size_t)NN * F1C, F1C,
            h2F, (size_t)NN * F1C, NN, F1C, nullptr, 0, nullptr);
        // 4. s0 = h2 @ W2^T + b2  (VALU, proven)
        gemm64_k<float, float><<<dim3(128, 8, 1), 256, 0, stream>>>(
            h2F, 0, F1C, W2, 0, F1C, s0F, 0, F1C, F2C, b2, nullptr, 0, 0, 1, 1);
        l2relu_k<<<NB * NN, 64, 0, stream>>>(s0F, F2C);
        bn_k<<<NN, 256, 0, stream>>>(s0F, g2, be2, 9);
        // 5. prox x10 (MFMA dbuf, f64 state): s0F -> D1; ping-pong; it9 -> D2
        mf_k<float, double, true, 2><<<dim3(16, 4, 8), 256, 0, stream>>>(
            adj, (size_t)NN * NN, NN, s0F, (size_t)NN * F2C, F2C,
            D1, (size_t)NN * F2C, NN, F2C, s0F, (size_t)NN * F2C, degD);
        const double* Sin = D1;
        for (int it = 1; it < 10; ++it) {
            double* Sout = (it & 1) ? D2 : D1;
            mf_k<double, double, true, 2><<<dim3(16, 4, 8), 256, 0, stream>>>(
                adj, (size_t)NN * NN, NN, Sin, (size_t)NN * F2C, F2C,
                Sout, (size_t)NN * F2C, NN, F2C, s0F, (size_t)NN * F2C, degD);
            Sin = Sout;
        }
        softmax_k<double><<<NB * NN, 256, 0, stream>>>(D2, out);
    } else if (tier == 1) {
        float* R0 = ws;
        float* R1 = ws + M2;
        float* aggF = R1;
        float* t1F = R0;
        float* h2F = R1;
        float* s0F = R0;

        gemm64_k<float, float><<<dim3(16, 4, 8), 256, 0, stream>>>(
            adj, (size_t)NN * NN, NN, x, (size_t)NN * F0C, F0C,
            aggF, (size_t)NN * F0C, NN, F0C, nullptr, nullptr, 0, 0, 0, 0);
        gemm64_k<float, float><<<dim3(128, 2, 1), 256, 0, stream>>>(
            aggF, 0, F0C, W1, 0, F0C, t1F, 0, F0C, F1C, b1, nullptr, 0, 0, 1, 1);
        l2relu_k<<<NB * NN, 64, 0, stream>>>(t1F, F1C);
        bn_k<<<NN, 256, 0, stream>>>(t1F, g1, be1, 7);
        gemm64_k<float, float><<<dim3(16, 2, 8), 256, 0, stream>>>(
            adj, (size_t)NN * NN, NN, t1F, (size_t)NN * F1C, F1C,
            h2F, (size_t)NN * F1C, NN, F1C, nullptr, nullptr, 0, 0, 0, 0);
        gemm64_k<float, float><<<dim3(128, 8, 1), 256, 0, stream>>>(
            h2F, 0, F1C, W2, 0, F1C, s0F, 0, F1C, F2C, b2, nullptr, 0, 0, 1, 1);
        l2relu_k<<<NB * NN, 64, 0, stream>>>(s0F, F2C);
        bn_k<<<NN, 256, 0, stream>>>(s0F, g2, be2, 9);
        const float* Sin = s0F;
        for (int it = 0; it < 10; ++it) {
            float* Sout = (it & 1) ? out : R1;
            gemm64_k<float, float><<<dim3(16, 8, 8), 256, 0, stream>>>(
                adj, (size_t)NN * NN, NN, Sin, (size_t)NN * F2C, F2C,
                Sout, (size_t)NN * F2C, NN, F2C, nullptr, s0F, (size_t)NN * F2C, 1, 0, 2);
            Sin = Sout;
        }
        softmax_k<float><<<NB * NN, 256, 0, stream>>>(out, out);
    } else {
        float* Wp0 = ws;
        float* Wp1 = ws + (size_t)NN * F2C;
        float* xW1 = ws;
        float* t1 = out;
        float* h2 = ws;
        float* s0 = out;

        gemm64_k<float, float><<<dim3(128, 2, 1), 256, 0, stream>>>(
            x, 0, F0C, W1, 0, F0C, xW1, 0, F0C, F1C, nullptr, nullptr, 0, 0, 1, 0);
        gemm64_k<float, float><<<dim3(16, 2, 8), 256, 0, stream>>>(
            adj, (size_t)NN * NN, NN, xW1, (size_t)NN * F1C, F1C,
            t1, (size_t)NN * F1C, NN, F1C, b1, nullptr, 0, 0, 0, 1);
        l2relu_k<<<NB * NN, 64, 0, stream>>>(t1, F1C);
        bn_k<<<NN, 256, 0, stream>>>(t1, g1, be1, 7);
        gemm64_k<float, float><<<dim3(16, 2, 8), 256, 0, stream>>>(
            adj, (size_t)NN * NN, NN, t1, (size_t)NN * F1C, F1C,
            h2, (size_t)NN * F1C, NN, F1C, nullptr, nullptr, 0, 0, 0, 0);
        gemm64_k<float, float><<<dim3(128, 8, 1), 256, 0, stream>>>(
            h2, 0, F1C, W2, 0, F1C, s0, 0, F1C, F2C, b2, nullptr, 0, 0, 1, 1);
        l2relu_k<<<NB * NN, 64, 0, stream>>>(s0, F2C);
        bn_k<<<NN, 256, 0, stream>>>(s0, g2, be2, 9);
        for (int b = 0; b < NB; ++b) {
            float* s0b = out + (size_t)b * NN * F2C;
            const float* Ab = adj + (size_t)b * NN * NN;
            const float* Sin = s0b;
            for (int it = 0; it < 10; ++it) {
                float* Sout = (it == 9) ? s0b : ((it & 1) ? Wp1 : Wp0);
                gemm64_k<float, float><<<dim3(16, 8, 1), 256, 0, stream>>>(
                    Ab, 0, NN, Sin, 0, F2C,
                    Sout, 0, NN, F2C, nullptr, s0b, 0, 1, 0, 2);
                Sin = Sout;
            }
        }
        softmax_k<float><<<NB * NN, 256, 0, stream>>>(out, out);
    }
}

// Round 11
// 6444.333 us; speedup vs baseline: 1.2595x; 1.2595x over previous
//
#include <hip/hip_runtime.h>
#include <cstdint>
#include <cstddef>

#define NN 2048
#define NB 8
#define F0C 256
#define F1C 128
#define F2C 512

typedef double f64x4 __attribute__((ext_vector_type(4)));

// ---------------- helpers ----------------
__device__ __forceinline__ double waveSumD(double v) {
#pragma unroll
    for (int o = 32; o; o >>= 1) v += __shfl_down(v, o, 64);
    return v;
}

// ---------------- deg[row] = f64 rowsum of adj row ----------------
__global__ __launch_bounds__(256) void deg_k(const float* __restrict__ adj,
                                             double* __restrict__ degD) {
    const size_t row = blockIdx.x;
    const float4* r4 = (const float4*)(adj + row * (size_t)NN);
    float4 a = r4[threadIdx.x];
    float4 b = r4[threadIdx.x + 256];
    double s = (((double)a.x + a.y) + ((double)a.z + a.w)) +
               (((double)b.x + b.y) + ((double)b.z + b.w));
    s = waveSumD(s);
    __shared__ double red[4];
    if (!(threadIdx.x & 63)) red[threadIdx.x >> 6] = s;
    __syncthreads();
    if (!threadIdx.x) degD[row] = (red[0] + red[1]) + (red[2] + red[3]);
}

// ---------------- f64 MFMA GEMM, double-buffered, named-register staging ----------
// mode-3 mapping (HW-verified r8):
//   A: lane l holds A[row=l&15][k=l>>4]
//   B: lane l holds B[k=l>>4][col=l&15]
//   D: lane l, reg v holds D[row=(l>>4)+4*v][col=l&15]
// Pipeline per 2 k-steps (nk even at all call sites):
//   LOAD(k+1) | COMPUTE(buf0) | STORE(buf1) | bar | LOAD(k+2) | COMPUTE(buf1) | STORE(buf0) | bar
// Staging lives in NAMED registers (no arrays/lambdas -> no scratch demotion; r10 lesson).
template <typename BT, typename CT, bool ADD_AT, int EPI>
__global__ __launch_bounds__(256, 2) void mf_k(
    const float* __restrict__ A, size_t Abatch, int lda,
    const BT* __restrict__ Bm, size_t Bbatch, int ldb,
    CT* __restrict__ Cout, size_t Cbatch, int K, int Ccols,
    const float* __restrict__ S0, size_t Sbatch,
    const double* __restrict__ degD) {
    __shared__ float As[2][128][20];                  // [buf][i][k]
    __shared__ float AsT[2][ADD_AT ? 16 : 1][136];    // [buf][k][i]
    __shared__ BT Bs[2][16][132];                     // [buf][k][j]
    __shared__ double degL[EPI == 2 ? 128 : 1];

    const int b = blockIdx.z;
    const int i0 = blockIdx.x * 128;
    const int j0 = blockIdx.y * 128;
    const float* Ab = A + Abatch * (size_t)b;
    const BT* Bb = Bm + Bbatch * (size_t)b;
    const int t = threadIdx.x;
    const int l = t & 63;
    const int wv = t >> 6;
    const int wr = (wv >> 1) * 64;   // wave row base in tile
    const int wc = (wv & 1) * 64;    // wave col base in tile
    const int lr = l & 15;           // A-row / B-col / D-col lane index
    const int lk = l >> 4;           // k lane index (0..3); D rows = lk + 4v

    // staging indices
    const int sa_i = t >> 2, sa_q = (t & 3) * 4;   // A: rows sa_i, sa_i+64; cols sa_q..+3
    const int sb_k = t >> 5, sb_c = (t & 31) * 4;  // AT/B: rows sb_k, sb_k+8; cols sb_c..+3

    // staging registers — individually named (never address-taken)
    float4 aR0, aR1;
    float4 tR0, tR1;
    double2 bD0, bD1, bD2, bD3;
    float4 bF0, bF1;

#define MF_LOAD(K0)                                                              \
    {                                                                            \
        const int _k0 = (K0);                                                    \
        aR0 = *(const float4*)(Ab + (size_t)(i0 + sa_i) * lda + _k0 + sa_q);     \
        aR1 = *(const float4*)(Ab + (size_t)(i0 + sa_i + 64) * lda + _k0 + sa_q);\
        if constexpr (ADD_AT) {                                                  \
            tR0 = *(const float4*)(Ab + (size_t)(_k0 + sb_k) * lda + i0 + sb_c); \
            tR1 = *(const float4*)(Ab + (size_t)(_k0 + sb_k + 8) * lda + i0 + sb_c);\
        }                                                                        \
        if constexpr (sizeof(BT) == 8) {                                         \
            const BT* _s0 = Bb + (size_t)(_k0 + sb_k) * ldb + j0 + sb_c;         \
            const BT* _s1 = Bb + (size_t)(_k0 + sb_k + 8) * ldb + j0 + sb_c;     \
            bD0 = *(const double2*)_s0; bD1 = *(const double2*)(_s0 + 2);        \
            bD2 = *(const double2*)_s1; bD3 = *(const double2*)(_s1 + 2);        \
        } else {                                                                 \
            bF0 = *(const float4*)(Bb + (size_t)(_k0 + sb_k) * ldb + j0 + sb_c); \
            bF1 = *(const float4*)(Bb + (size_t)(_k0 + sb_k + 8) * ldb + j0 + sb_c);\
        }                                                                        \
    }

#define MF_STORE(BF)                                                             \
    {                                                                            \
        *(float4*)&As[BF][sa_i][sa_q] = aR0;                                     \
        *(float4*)&As[BF][sa_i + 64][sa_q] = aR1;                                \
        if constexpr (ADD_AT) {                                                  \
            *(float4*)&AsT[BF][sb_k][sb_c] = tR0;                                \
            *(float4*)&AsT[BF][sb_k + 8][sb_c] = tR1;                            \
        }                                                                        \
        if constexpr (sizeof(BT) == 8) {                                         \
            *(double2*)&Bs[BF][sb_k][sb_c] = bD0;                                \
            *(double2*)&Bs[BF][sb_k][sb_c + 2] = bD1;                            \
            *(double2*)&Bs[BF][sb_k + 8][sb_c] = bD2;                            \
            *(double2*)&Bs[BF][sb_k + 8][sb_c + 2] = bD3;                        \
        } else {                                                                 \
            *(float4*)&Bs[BF][sb_k][sb_c] = bF0;                                 \
            *(float4*)&Bs[BF][sb_k + 8][sb_c] = bF1;                             \
        }                                                                        \
    }

#define MF_COMP(CUR)                                                             \
    {                                                                            \
        _Pragma("unroll")                                                        \
        for (int kk = 0; kk < 4; ++kk) {                                         \
            const int kr = kk * 4 + lk;                                          \
            double av[4], bv[4];                                                 \
            _Pragma("unroll")                                                    \
            for (int r = 0; r < 4; ++r) {                                        \
                const int ii = wr + r * 16 + lr;                                 \
                double a = (double)As[CUR][ii][kr];                              \
                if constexpr (ADD_AT) a += (double)AsT[CUR][kr][ii];             \
                av[r] = a;                                                       \
            }                                                                    \
            _Pragma("unroll")                                                    \
            for (int c = 0; c < 4; ++c)                                          \
                bv[c] = (double)Bs[CUR][kr][wc + c * 16 + lr];                   \
            _Pragma("unroll")                                                    \
            for (int r = 0; r < 4; ++r)                                          \
                _Pragma("unroll")                                                \
                for (int c = 0; c < 4; ++c)                                      \
                    acc[r][c] = __builtin_amdgcn_mfma_f64_16x16x4f64(            \
                        av[r], bv[c], acc[r][c], 0, 0, 0);                       \
        }                                                                        \
    }

    f64x4 acc[4][4];
#pragma unroll
    for (int r = 0; r < 4; ++r)
#pragma unroll
        for (int c = 0; c < 4; ++c)
#pragma unroll
            for (int v = 0; v < 4; ++v) acc[r][c][v] = 0.0;

    if (EPI == 2) {
        if (t < 128) degL[t] = degD[(size_t)b * NN + i0 + t];
    }

    const int nk = K / 16;  // even at all call sites (128 / 16 / 8)
    MF_LOAD(0);
    MF_STORE(0);
    __syncthreads();

    for (int ks = 0; ks < nk; ks += 2) {
        MF_LOAD((ks + 1) * 16);
        MF_COMP(0);
        MF_STORE(1);
        __syncthreads();
        if (ks + 2 < nk) MF_LOAD((ks + 2) * 16);
        MF_COMP(1);
        if (ks + 2 < nk) {
            MF_STORE(0);
            __syncthreads();
        }
    }
#undef MF_LOAD
#undef MF_STORE
#undef MF_COMP

    // epilogue (D: row = lk + 4v, col = lr)
#pragma unroll
    for (int r = 0; r < 4; ++r) {
#pragma unroll
        for (int v = 0; v < 4; ++v) {
            const int rl = wr + r * 16 + lk + 4 * v;
            const size_t grow = (size_t)(i0 + rl);
            double cA = 0.0;
            if (EPI == 2) cA = 0.8 - 0.02 * degL[rl];
#pragma unroll
            for (int c = 0; c < 4; ++c) {
                const int gcol = j0 + wc + c * 16 + lr;
                double y = acc[r][c][v];
                if (EPI == 2) {
                    const double sv = (double)Bb[grow * (size_t)ldb + gcol];
                    const double s0v =
                        (double)S0[Sbatch * (size_t)b + grow * (size_t)Ccols + gcol];
                    const double u = cA * sv + 0.01 * y + 0.2 * s0v;
                    y = (u > 0.1) ? (u - 0.1) : ((u < -0.1) ? (u + 0.1) : 0.0);
                }
                Cout[Cbatch * (size_t)b + grow * (size_t)Ccols + gcol] = (CT)y;
            }
        }
    }
}

// ---------------- fp64-accumulating VALU GEMM (round-5 verbatim; weight GEMMs) ----
template <typename BT, typename CT>
__global__ __launch_bounds__(256) void gemm64_k(
    const float* __restrict__ A, size_t Abatch, int lda,
    const BT* __restrict__ Bm, size_t Bbatch, int ldb,
    CT* __restrict__ Cout, size_t Cbatch,
    int K, int Ccols,
    const float* __restrict__ bias,
    const float* __restrict__ S0, size_t Sbatch,
    int addAT, int btrans, int epi) {
    __shared__ float As[32][132];
    __shared__ float AsT[32][132];
    __shared__ BT Bs[32][68];
    __shared__ double degLDS[2][128];
    const int b = blockIdx.z;
    const int i0 = blockIdx.x * 128;
    const int j0 = blockIdx.y * 64;
    const float* Ab = A + Abatch * (size_t)b;
    const BT* Bb = Bm + Bbatch * (size_t)b;
    const int t = threadIdx.x;
    const int wv = t >> 6, ln = t & 63;
    const int ri = (wv >> 1) * 64 + (ln >> 3) * 8;
    const int rj = ((wv & 1) * 8 + (ln & 7)) * 4;

    double acc[8][4];
#pragma unroll
    for (int i = 0; i < 8; ++i)
#pragma unroll
        for (int j = 0; j < 4; ++j) acc[i][j] = 0.0;

    const int a_i = t >> 1, a_m = (t & 1) * 16;
    const int p_m = t >> 3, p_i = (t & 7) * 16;
    const int b_m = t >> 3, b_j = (t & 7) * 8;
    const int w_j = t >> 2, w_m = (t & 3) * 8;
    double degacc = 0.0;

    for (int k0 = 0; k0 < K; k0 += 32) {
        if (k0) __syncthreads();
        {
            const float4* src =
                (const float4*)(Ab + (size_t)(i0 + a_i) * lda + k0 + a_m);
            float4 v0 = src[0], v1 = src[1], v2 = src[2], v3 = src[3];
            if (epi == 2)
                degacc += (((double)v0.x + v0.y) + ((double)v0.z + v0.w)) +
                          (((double)v1.x + v1.y) + ((double)v1.z + v1.w)) +
                          (((double)v2.x + v2.y) + ((double)v2.z + v2.w)) +
                          (((double)v3.x + v3.y) + ((double)v3.z + v3.w));
            As[a_m + 0][a_i] = v0.x;  As[a_m + 1][a_i] = v0.y;
            As[a_m + 2][a_i] = v0.z;  As[a_m + 3][a_i] = v0.w;
            As[a_m + 4][a_i] = v1.x;  As[a_m + 5][a_i] = v1.y;
            As[a_m + 6][a_i] = v1.z;  As[a_m + 7][a_i] = v1.w;
            As[a_m + 8][a_i] = v2.x;  As[a_m + 9][a_i] = v2.y;
            As[a_m + 10][a_i] = v2.z; As[a_m + 11][a_i] = v2.w;
            As[a_m + 12][a_i] = v3.x; As[a_m + 13][a_i] = v3.y;
            As[a_m + 14][a_i] = v3.z; As[a_m + 15][a_i] = v3.w;
        }
        if (addAT) {
            const float4* src =
                (const float4*)(Ab + (size_t)(k0 + p_m) * lda + i0 + p_i);
            float4 v0 = src[0], v1 = src[1], v2 = src[2], v3 = src[3];
            AsT[p_m][p_i + 0] = v0.x;  AsT[p_m][p_i + 1] = v0.y;
            AsT[p_m][p_i + 2] = v0.z;  AsT[p_m][p_i + 3] = v0.w;
            AsT[p_m][p_i + 4] = v1.x;  AsT[p_m][p_i + 5] = v1.y;
            AsT[p_m][p_i + 6] = v1.z;  AsT[p_m][p_i + 7] = v1.w;
            AsT[p_m][p_i + 8] = v2.x;  AsT[p_m][p_i + 9] = v2.y;
            AsT[p_m][p_i + 10] = v2.z; AsT[p_m][p_i + 11] = v2.w;
            AsT[p_m][p_i + 12] = v3.x; AsT[p_m][p_i + 13] = v3.y;
            AsT[p_m][p_i + 14] = v3.z; AsT[p_m][p_i + 15] = v3.w;
        }
        if (!btrans) {
            const BT* src = Bb + (size_t)(k0 + b_m) * ldb + j0 + b_j;
            if constexpr (sizeof(BT) == 8) {
                const double2* s2 = (const double2*)src;
                double2 u0 = s2[0], u1 = s2[1], u2 = s2[2], u3 = s2[3];
                Bs[b_m][b_j + 0] = (BT)u0.x; Bs[b_m][b_j + 1] = (BT)u0.y;
                Bs[b_m][b_j + 2] = (BT)u1.x; Bs[b_m][b_j + 3] = (BT)u1.y;
                Bs[b_m][b_j + 4] = (BT)u2.x; Bs[b_m][b_j + 5] = (BT)u2.y;
                Bs[b_m][b_j + 6] = (BT)u3.x; Bs[b_m][b_j + 7] = (BT)u3.y;
            } else {
                const float4* s4 = (const float4*)src;
                float4 u0 = s4[0], u1 = s4[1];
                Bs[b_m][b_j + 0] = (BT)u0.x; Bs[b_m][b_j + 1] = (BT)u0.y;
                Bs[b_m][b_j + 2] = (BT)u0.z; Bs[b_m][b_j + 3] = (BT)u0.w;
                Bs[b_m][b_j + 4] = (BT)u1.x; Bs[b_m][b_j + 5] = (BT)u1.y;
                Bs[b_m][b_j + 6] = (BT)u1.z; Bs[b_m][b_j + 7] = (BT)u1.w;
            }
        } else {
            const float* Wf = reinterpret_cast<const float*>(Bm);
            const float4* src =
                (const float4*)(Wf + (size_t)(j0 + w_j) * ldb + k0 + w_m);
            float4 v0 = src[0], v1 = src[1];
            Bs[w_m + 0][w_j] = (BT)v0.x; Bs[w_m + 1][w_j] = (BT)v0.y;
            Bs[w_m + 2][w_j] = (BT)v0.z; Bs[w_m + 3][w_j] = (BT)v0.w;
            Bs[w_m + 4][w_j] = (BT)v1.x; Bs[w_m + 5][w_j] = (BT)v1.y;
            Bs[w_m + 6][w_j] = (BT)v1.z; Bs[w_m + 7][w_j] = (BT)v1.w;
        }
        __syncthreads();
#pragma unroll 4
        for (int mk = 0; mk < 32; ++mk) {
            float4 a0 = *(const float4*)&As[mk][ri];
            float4 a1 = *(const float4*)&As[mk][ri + 4];
            double ad[8] = {a0.x, a0.y, a0.z, a0.w, a1.x, a1.y, a1.z, a1.w};
            if (addAT) {
                float4 t0 = *(const float4*)&AsT[mk][ri];
                float4 t1 = *(const float4*)&AsT[mk][ri + 4];
                ad[0] += t0.x; ad[1] += t0.y; ad[2] += t0.z; ad[3] += t0.w;
                ad[4] += t1.x; ad[5] += t1.y; ad[6] += t1.z; ad[7] += t1.w;
            }
            double bd[4];
#pragma unroll
            for (int c = 0; c < 4; ++c) bd[c] = (double)Bs[mk][rj + c];
#pragma unroll
            for (int iy = 0; iy < 8; ++iy)
#pragma unroll
                for (int jx = 0; jx < 4; ++jx)
                    acc[iy][jx] = fma(ad[iy], bd[jx], acc[iy][jx]);
        }
    }

    if (epi == 2) degLDS[t & 1][t >> 1] = degacc;
    __syncthreads();

#pragma unroll
    for (int iy = 0; iy < 8; ++iy) {
        const int row = i0 + ri + iy;
        CT* cp = Cout + Cbatch * (size_t)b + (size_t)row * Ccols + j0 + rj;
        CT o[4];
        if (epi == 0) {
#pragma unroll
            for (int jx = 0; jx < 4; ++jx) o[jx] = (CT)acc[iy][jx];
        } else if (epi == 1) {
#pragma unroll
            for (int jx = 0; jx < 4; ++jx)
                o[jx] = (CT)(acc[iy][jx] + (double)bias[j0 + rj + jx]);
        } else {
            const double dg = degLDS[0][ri + iy] + degLDS[1][ri + iy];
            const double cA = 0.8 - 0.02 * dg;
            const BT* sp = Bb + (size_t)row * ldb + j0 + rj;
            const float* s0p = S0 + Sbatch * (size_t)b + (size_t)row * Ccols + j0 + rj;
#pragma unroll
            for (int jx = 0; jx < 4; ++jx) {
                const double u = cA * (double)sp[jx] + 0.01 * acc[iy][jx] +
                                 0.2 * (double)s0p[jx];
                const double v = (u > 0.1) ? (u - 0.1) : ((u < -0.1) ? (u + 0.1) : 0.0);
                o[jx] = (CT)v;
            }
        }
        if constexpr (sizeof(CT) == 8) {
            double2 q0, q1;
            q0.x = o[0]; q0.y = o[1]; q1.x = o[2]; q1.y = o[3];
            *(double2*)cp = q0;
            *(double2*)(cp + 2) = q1;
        } else {
            *(float4*)cp = make_float4(o[0], o[1], o[2], o[3]);
        }
    }
}

// ---------------- row L2-normalize + relu ----------------
__global__ __launch_bounds__(64) void l2relu_k(float* __restrict__ buf, int F) {
    const size_t row = blockIdx.x;
    float* p = buf + row * (size_t)F;
    double ss = 0.0;
    for (int k = threadIdx.x; k < F; k += 64) {
        const double v = (double)p[k];
        ss += v * v;
    }
#pragma unroll
    for (int o = 32; o; o >>= 1) ss += __shfl_xor(ss, o, 64);
    const double den = fmax(sqrt(ss), 1e-12);
    for (int k = threadIdx.x; k < F; k += 64) {
        const double v = (double)p[k] / den;
        p[k] = (float)(v > 0.0 ? v : 0.0);
    }
}

// ---------------- BatchNorm per node, f64 two-pass ----------------
__global__ __launch_bounds__(256) void bn_k(float* __restrict__ buf,
                                            const float* __restrict__ g,
                                            const float* __restrict__ be, int fl) {
    const int n = blockIdx.x;
    const int F = 1 << fl;
    const int total = NB << fl;
    __shared__ double red[4];
    __shared__ double sh_m, sh_scale, sh_be;
    const int wv = threadIdx.x >> 6, ln = threadIdx.x & 63;
    double s = 0.0;
    for (int idx = threadIdx.x; idx < total; idx += 256) {
        const int bb = idx >> fl, f = idx & (F - 1);
        s += (double)buf[((size_t)bb * NN + n) * F + f];
    }
    s = waveSumD(s);
    if (!ln) red[wv] = s;
    __syncthreads();
    if (!threadIdx.x) sh_m = ((red[0] + red[1]) + (red[2] + red[3])) / (double)total;
    __syncthreads();
    const double m = sh_m;
    double v2 = 0.0;
    for (int idx = threadIdx.x; idx < total; idx += 256) {
        const int bb = idx >> fl, f = idx & (F - 1);
        const double d = (double)buf[((size_t)bb * NN + n) * F + f] - m;
        v2 += d * d;
    }
    v2 = waveSumD(v2);
    __syncthreads();
    if (!ln) red[wv] = v2;
    __syncthreads();
    if (!threadIdx.x) {
        const double var = ((red[0] + red[1]) + (red[2] + red[3])) / (double)total;
        sh_scale = (1.0 / sqrt(var + 1e-5)) * (double)g[n];
        sh_be = (double)be[n];
    }
    __syncthreads();
    const double sc = sh_scale, bb2 = sh_be;
    for (int idx = threadIdx.x; idx < total; idx += 256) {
        const int bb = idx >> fl, f = idx & (F - 1);
        float* pp = &buf[((size_t)bb * NN + n) * F + f];
        *pp = (float)(((double)*pp - m) * sc + bb2);
    }
}

// ---------------- softmax over last dim (512) ----------------
template <typename T>
__global__ __launch_bounds__(256) void softmax_k(const T* __restrict__ in,
                                                 float* __restrict__ out) {
    const size_t row = blockIdx.x;
    const T* p = in + row * (size_t)F2C;
    float* q = out + row * (size_t)F2C;
    const int t = threadIdx.x;
    const int wv = t >> 6, ln = t & 63;
    const double v0 = (double)p[t], v1 = (double)p[t + 256];
    double m = fmax(v0, v1);
#pragma unroll
    for (int o = 32; o; o >>= 1) m = fmax(m, __shfl_xor(m, o, 64));
    __shared__ double red[4];
    if (!ln) red[wv] = m;
    __syncthreads();
    m = fmax(fmax(red[0], red[1]), fmax(red[2], red[3]));
    const double e0 = exp(v0 - m), e1 = exp(v1 - m);
    double s = e0 + e1;
#pragma unroll
    for (int o = 32; o; o >>= 1) s += __shfl_xor(s, o, 64);
    __syncthreads();
    if (!ln) red[wv] = s;
    __syncthreads();
    s = (red[0] + red[1]) + (red[2] + red[3]);
    q[t] = (float)(e0 / s);
    q[t + 256] = (float)(e1 / s);
}

extern "C" void kernel_launch(void* const* d_in, const int* in_sizes, int n_in,
                              void* d_out, int out_size, void* d_ws, size_t ws_size,
                              hipStream_t stream) {
    const float* x = (const float*)d_in[0];
    const float* adj = (const float*)d_in[1];
    const float* W1 = (const float*)d_in[2];
    const float* b1 = (const float*)d_in[3];
    const float* g1 = (const float*)d_in[4];
    const float* be1 = (const float*)d_in[5];
    const float* W2 = (const float*)d_in[6];
    const float* b2 = (const float*)d_in[7];
    const float* g2 = (const float*)d_in[8];
    const float* be2 = (const float*)d_in[9];
    float* out = (float*)d_out;
    float* ws = (float*)d_ws;

    const size_t M2 = (size_t)NB * NN * F2C;     // 8,388,608 floats
    const size_t szAgg = (size_t)NB * NN * F0C;  // 4,194,304 floats

    const int tier = (ws_size >= ((size_t)192 << 20)) ? 0
                   : (ws_size >= ((size_t)64 << 20)) ? 1 : 2;

    if (tier == 0) {
        // [s0F 32MiB][tmpF 32MiB][D1 64MiB][D2 64MiB]; degD in dead tmpF hole.
        float* s0F = ws;
        float* tmpF = ws + M2;
        double* D1 = (double*)(ws + 2 * M2);
        double* D2 = D1 + M2;
        float* aggF = tmpF;                          // 16 MiB
        float* t1F = tmpF + szAgg;                   // 8 MiB at +16 MiB
        float* h2F = tmpF;                           // reuses agg (dead)
        double* degD = (double*)(tmpF + 7340032);    // +28 MiB, 128 KiB

        deg_k<<<NB * NN, 256, 0, stream>>>(adj, degD);
        // 1. agg = adj @ x  (MFMA)
        mf_k<float, float, false, 0><<<dim3(16, 2, 8), 256, 0, stream>>>(
            adj, (size_t)NN * NN, NN, x, (size_t)NN * F0C, F0C,
            aggF, (size_t)NN * F0C, NN, F0C, nullptr, 0, nullptr);
        // 2. t1 = agg @ W1^T + b1  (VALU, proven)
        gemm64_k<float, float><<<dim3(128, 2, 1), 256, 0, stream>>>(
            aggF, 0, F0C, W1, 0, F0C, t1F, 0, F0C, F1C, b1, nullptr, 0, 0, 1, 1);
        l2relu_k<<<NB * NN, 64, 0, stream>>>(t1F, F1C);
        bn_k<<<NN, 256, 0, stream>>>(t1F, g1, be1, 7);
        // 3. h2 = adj @ t1  (MFMA)
        mf_k<float, float, false, 0><<<dim3(16, 1, 8), 256, 0, stream>>>(
            adj, (size_t)NN * NN, NN, t1F, (size_t)NN * F1C, F1C,
            h2F, (size_t)NN * F1C, NN, F1C, nullptr, 0, nullptr);
        // 4. s0 = h2 @ W2^T + b2  (VALU, proven)
        gemm64_k<float, float><<<dim3(128, 8, 1), 256, 0, stream>>>(
            h2F, 0, F1C, W2, 0, F1C, s0F, 0, F1C, F2C, b2, nullptr, 0, 0, 1, 1);
        l2relu_k<<<NB * NN, 64, 0, stream>>>(s0F, F2C);
        bn_k<<<NN, 256, 0, stream>>>(s0F, g2, be2, 9);
        // 5. prox x10 (MFMA dbuf, f64 state): s0F -> D1; ping-pong; it9 -> D2
        mf_k<float, double, true, 2><<<dim3(16, 4, 8), 256, 0, stream>>>(
            adj, (size_t)NN * NN, NN, s0F, (size_t)NN * F2C, F2C,
            D1, (size_t)NN * F2C, NN, F2C, s0F, (size_t)NN * F2C, degD);
        const double* Sin = D1;
        for (int it = 1; it < 10; ++it) {
            double* Sout = (it & 1) ? D2 : D1;
            mf_k<double, double, true, 2><<<dim3(16, 4, 8), 256, 0, stream>>>(
                adj, (size_t)NN * NN, NN, Sin, (size_t)NN * F2C, F2C,
                Sout, (size_t)NN * F2C, NN, F2C, s0F, (size_t)NN * F2C, degD);
            Sin = Sout;
        }
        softmax_k<double><<<NB * NN, 256, 0, stream>>>(D2, out);
    } else if (tier == 1) {
        float* R0 = ws;
        float* R1 = ws + M2;
        float* aggF = R1;
        float* t1F = R0;
        float* h2F = R1;
        float* s0F = R0;

        gemm64_k<float, float><<<dim3(16, 4, 8), 256, 0, stream>>>(
            adj, (size_t)NN * NN, NN, x, (size_t)NN * F0C, F0C,
            aggF, (size_t)NN * F0C, NN, F0C, nullptr, nullptr, 0, 0, 0, 0);
        gemm64_k<float, float><<<dim3(128, 2, 1), 256, 0, stream>>>(
            aggF, 0, F0C, W1, 0, F0C, t1F, 0, F0C, F1C, b1, nullptr, 0, 0, 1, 1);
        l2relu_k<<<NB * NN, 64, 0, stream>>>(t1F, F1C);
        bn_k<<<NN, 256, 0, stream>>>(t1F, g1, be1, 7);
        gemm64_k<float, float><<<dim3(16, 2, 8), 256, 0, stream>>>(
            adj, (size_t)NN * NN, NN, t1F, (size_t)NN * F1C, F1C,
            h2F, (size_t)NN * F1C, NN, F1C, nullptr, nullptr, 0, 0, 0, 0);
        gemm64_k<float, float><<<dim3(128, 8, 1), 256, 0, stream>>>(
            h2F, 0, F1C, W2, 0, F1C, s0F, 0, F1C, F2C, b2, nullptr, 0, 0, 1, 1);
        l2relu_k<<<NB * NN, 64, 0, stream>>>(s0F, F2C);
        bn_k<<<NN, 256, 0, stream>>>(s0F, g2, be2, 9);
        const float* Sin = s0F;
        for (int it = 0; it < 10; ++it) {
            float* Sout = (it & 1) ? out : R1;
            gemm64_k<float, float><<<dim3(16, 8, 8), 256, 0, stream>>>(
                adj, (size_t)NN * NN, NN, Sin, (size_t)NN * F2C, F2C,
                Sout, (size_t)NN * F2C, NN, F2C, nullptr, s0F, (size_t)NN * F2C, 1, 0, 2);
            Sin = Sout;
        }
        softmax_k<float><<<NB * NN, 256, 0, stream>>>(out, out);
    } else {
        float* Wp0 = ws;
        float* Wp1 = ws + (size_t)NN * F2C;
        float* xW1 = ws;
        float* t1 = out;
        float* h2 = ws;
        float* s0 = out;

        gemm64_k<float, float><<<dim3(128, 2, 1), 256, 0, stream>>>(
            x, 0, F0C, W1, 0, F0C, xW1, 0, F0C, F1C, nullptr, nullptr, 0, 0, 1, 0);
        gemm64_k<float, float><<<dim3(16, 2, 8), 256, 0, stream>>>(
            adj, (size_t)NN * NN, NN, xW1, (size_t)NN * F1C, F1C,
            t1, (size_t)NN * F1C, NN, F1C, b1, nullptr, 0, 0, 0, 1);
        l2relu_k<<<NB * NN, 64, 0, stream>>>(t1, F1C);
        bn_k<<<NN, 256, 0, stream>>>(t1, g1, be1, 7);
        gemm64_k<float, float><<<dim3(16, 2, 8), 256, 0, stream>>>(
            adj, (size_t)NN * NN, NN, t1, (size_t)NN * F1C, F1C,
            h2, (size_t)NN * F1C, NN, F1C, nullptr, nullptr, 0, 0, 0, 0);
        gemm64_k<float, float><<<dim3(128, 8, 1), 256, 0, stream>>>(
            h2, 0, F1C, W2, 0, F1C, s0, 0, F1C, F2C, b2, nullptr, 0, 0, 1, 1);
        l2relu_k<<<NB * NN, 64, 0, stream>>>(s0, F2C);
        bn_k<<<NN, 256, 0, stream>>>(s0, g2, be2, 9);
        for (int b = 0; b < NB; ++b) {
            float* s0b = out + (size_t)b * NN * F2C;
            const float* Ab = adj + (size_t)b * NN * NN;
            const float* Sin = s0b;
            for (int it = 0; it < 10; ++it) {
                float* Sout = (it == 9) ? s0b : ((it & 1) ? Wp1 : Wp0);
                gemm64_k<float, float><<<dim3(16, 8, 1), 256, 0, stream>>>(
                    Ab, 0, NN, Sin, 0, F2C,
                    Sout, 0, NN, F2C, nullptr, s0b, 0, 1, 0, 2);
                Sin = Sout;
            }
        }
        softmax_k<float><<<NB * NN, 256, 0, stream>>>(out, out);
    }
}

// Round 12
// 6298.124 us; speedup vs baseline: 1.2887x; 1.0232x over previous
//
#include <hip/hip_runtime.h>
#include <cstdint>
#include <cstddef>

#define NN 2048
#define NB 8
#define F0C 256
#define F1C 128
#define F2C 512

typedef double f64x4 __attribute__((ext_vector_type(4)));

// ---------------- helpers ----------------
__device__ __forceinline__ double waveSumD(double v) {
#pragma unroll
    for (int o = 32; o; o >>= 1) v += __shfl_down(v, o, 64);
    return v;
}

// ---------------- deg[row] = f64 rowsum of adj row ----------------
__global__ __launch_bounds__(256) void deg_k(const float* __restrict__ adj,
                                             double* __restrict__ degD) {
    const size_t row = blockIdx.x;
    const float4* r4 = (const float4*)(adj + row * (size_t)NN);
    float4 a = r4[threadIdx.x];
    float4 b = r4[threadIdx.x + 256];
    double s = (((double)a.x + a.y) + ((double)a.z + a.w)) +
               (((double)b.x + b.y) + ((double)b.z + b.w));
    s = waveSumD(s);
    __shared__ double red[4];
    if (!(threadIdx.x & 63)) red[threadIdx.x >> 6] = s;
    __syncthreads();
    if (!threadIdx.x) degD[row] = (red[0] + red[1]) + (red[2] + red[3]);
}

// ---------------- f64 MFMA GEMM, double-buffered, store-interleaved ----------
// mode-3 mapping (HW-verified r8):
//   A: lane l holds A[row=l&15][k=l>>4]
//   B: lane l holds B[k=l>>4][col=l&15]
//   D: lane l, reg v holds D[row=(l>>4)+4*v][col=l&15]
// Pipeline per k-step: LOAD(k+1) | COMP(kk0,1) | STORE(other buf) | COMP(kk2,3) | bar
// STORE overlaps the second MFMA half on the LDS pipe (r11 lesson: the exposed
// STORE+barrier tail was the 26% MfmaUtil gap). setprio(1) wraps MFMA clusters (T5).
// Staging in NAMED registers (no arrays/lambdas -> no scratch demotion; r10 lesson).
template <typename BT, typename CT, bool ADD_AT, int EPI>
__global__ __launch_bounds__(256, 2) void mf_k(
    const float* __restrict__ A, size_t Abatch, int lda,
    const BT* __restrict__ Bm, size_t Bbatch, int ldb,
    CT* __restrict__ Cout, size_t Cbatch, int K, int Ccols,
    const float* __restrict__ S0, size_t Sbatch,
    const double* __restrict__ degD) {
    __shared__ float As[2][128][20];                  // [buf][i][k]
    __shared__ float AsT[2][ADD_AT ? 16 : 1][136];    // [buf][k][i]
    __shared__ BT Bs[2][16][132];                     // [buf][k][j]
    __shared__ double degL[EPI == 2 ? 128 : 1];

    const int b = blockIdx.z;
    const int i0 = blockIdx.x * 128;
    const int j0 = blockIdx.y * 128;
    const float* Ab = A + Abatch * (size_t)b;
    const BT* Bb = Bm + Bbatch * (size_t)b;
    const int t = threadIdx.x;
    const int l = t & 63;
    const int wv = t >> 6;
    const int wr = (wv >> 1) * 64;   // wave row base in tile
    const int wc = (wv & 1) * 64;    // wave col base in tile
    const int lr = l & 15;           // A-row / B-col / D-col lane index
    const int lk = l >> 4;           // k lane index (0..3); D rows = lk + 4v

    // staging indices
    const int sa_i = t >> 2, sa_q = (t & 3) * 4;   // A: rows sa_i, sa_i+64; cols sa_q..+3
    const int sb_k = t >> 5, sb_c = (t & 31) * 4;  // AT/B: rows sb_k, sb_k+8; cols sb_c..+3

    // staging registers — individually named (never address-taken)
    float4 aR0, aR1;
    float4 tR0, tR1;
    double2 bD0, bD1, bD2, bD3;
    float4 bF0, bF1;

#define MF_LOAD(K0)                                                              \
    {                                                                            \
        const int _k0 = (K0);                                                    \
        aR0 = *(const float4*)(Ab + (size_t)(i0 + sa_i) * lda + _k0 + sa_q);     \
        aR1 = *(const float4*)(Ab + (size_t)(i0 + sa_i + 64) * lda + _k0 + sa_q);\
        if constexpr (ADD_AT) {                                                  \
            tR0 = *(const float4*)(Ab + (size_t)(_k0 + sb_k) * lda + i0 + sb_c); \
            tR1 = *(const float4*)(Ab + (size_t)(_k0 + sb_k + 8) * lda + i0 + sb_c);\
        }                                                                        \
        if constexpr (sizeof(BT) == 8) {                                         \
            const BT* _s0 = Bb + (size_t)(_k0 + sb_k) * ldb + j0 + sb_c;         \
            const BT* _s1 = Bb + (size_t)(_k0 + sb_k + 8) * ldb + j0 + sb_c;     \
            bD0 = *(const double2*)_s0; bD1 = *(const double2*)(_s0 + 2);        \
            bD2 = *(const double2*)_s1; bD3 = *(const double2*)(_s1 + 2);        \
        } else {                                                                 \
            bF0 = *(const float4*)(Bb + (size_t)(_k0 + sb_k) * ldb + j0 + sb_c); \
            bF1 = *(const float4*)(Bb + (size_t)(_k0 + sb_k + 8) * ldb + j0 + sb_c);\
        }                                                                        \
    }

#define MF_STORE(BF)                                                             \
    {                                                                            \
        *(float4*)&As[BF][sa_i][sa_q] = aR0;                                     \
        *(float4*)&As[BF][sa_i + 64][sa_q] = aR1;                                \
        if constexpr (ADD_AT) {                                                  \
            *(float4*)&AsT[BF][sb_k][sb_c] = tR0;                                \
            *(float4*)&AsT[BF][sb_k + 8][sb_c] = tR1;                            \
        }                                                                        \
        if constexpr (sizeof(BT) == 8) {                                         \
            *(double2*)&Bs[BF][sb_k][sb_c] = bD0;                                \
            *(double2*)&Bs[BF][sb_k][sb_c + 2] = bD1;                            \
            *(double2*)&Bs[BF][sb_k + 8][sb_c] = bD2;                            \
            *(double2*)&Bs[BF][sb_k + 8][sb_c + 2] = bD3;                        \
        } else {                                                                 \
            *(float4*)&Bs[BF][sb_k][sb_c] = bF0;                                 \
            *(float4*)&Bs[BF][sb_k + 8][sb_c] = bF1;                             \
        }                                                                        \
    }

// one half of a k-step: kk = 2H, 2H+1 (32 MFMAs), wrapped in setprio
#define MF_COMP_HALF(CUR, H)                                                     \
    {                                                                            \
        __builtin_amdgcn_s_setprio(1);                                           \
        _Pragma("unroll")                                                        \
        for (int kk = 2 * (H); kk < 2 * (H) + 2; ++kk) {                         \
            const int kr = kk * 4 + lk;                                          \
            double av[4], bv[4];                                                 \
            _Pragma("unroll")                                                    \
            for (int r = 0; r < 4; ++r) {                                        \
                const int ii = wr + r * 16 + lr;                                 \
                double a = (double)As[CUR][ii][kr];                              \
                if constexpr (ADD_AT) a += (double)AsT[CUR][kr][ii];             \
                av[r] = a;                                                       \
            }                                                                    \
            _Pragma("unroll")                                                    \
            for (int c = 0; c < 4; ++c)                                          \
                bv[c] = (double)Bs[CUR][kr][wc + c * 16 + lr];                   \
            _Pragma("unroll")                                                    \
            for (int r = 0; r < 4; ++r)                                          \
                _Pragma("unroll")                                                \
                for (int c = 0; c < 4; ++c)                                      \
                    acc[r][c] = __builtin_amdgcn_mfma_f64_16x16x4f64(            \
                        av[r], bv[c], acc[r][c], 0, 0, 0);                       \
        }                                                                        \
        __builtin_amdgcn_s_setprio(0);                                           \
    }

    f64x4 acc[4][4];
#pragma unroll
    for (int r = 0; r < 4; ++r)
#pragma unroll
        for (int c = 0; c < 4; ++c)
#pragma unroll
            for (int v = 0; v < 4; ++v) acc[r][c][v] = 0.0;

    if (EPI == 2) {
        if (t < 128) degL[t] = degD[(size_t)b * NN + i0 + t];
    }

    const int nk = K / 16;  // even at all call sites (128 / 16 / 8)
    MF_LOAD(0);
    MF_STORE(0);
    __syncthreads();

    for (int ks = 0; ks < nk; ks += 2) {
        MF_LOAD((ks + 1) * 16);
        MF_COMP_HALF(0, 0);
        MF_STORE(1);                 // other buffer: overlaps second MFMA half
        MF_COMP_HALF(0, 1);
        __syncthreads();
        if (ks + 2 < nk) MF_LOAD((ks + 2) * 16);
        MF_COMP_HALF(1, 0);
        if (ks + 2 < nk) MF_STORE(0);
        MF_COMP_HALF(1, 1);
        if (ks + 2 < nk) __syncthreads();
    }
#undef MF_LOAD
#undef MF_STORE
#undef MF_COMP_HALF

    // epilogue (D: row = lk + 4v, col = lr)
#pragma unroll
    for (int r = 0; r < 4; ++r) {
#pragma unroll
        for (int v = 0; v < 4; ++v) {
            const int rl = wr + r * 16 + lk + 4 * v;
            const size_t grow = (size_t)(i0 + rl);
            double cA = 0.0;
            if (EPI == 2) cA = 0.8 - 0.02 * degL[rl];
#pragma unroll
            for (int c = 0; c < 4; ++c) {
                const int gcol = j0 + wc + c * 16 + lr;
                double y = acc[r][c][v];
                if (EPI == 2) {
                    const double sv = (double)Bb[grow * (size_t)ldb + gcol];
                    const double s0v =
                        (double)S0[Sbatch * (size_t)b + grow * (size_t)Ccols + gcol];
                    const double u = cA * sv + 0.01 * y + 0.2 * s0v;
                    y = (u > 0.1) ? (u - 0.1) : ((u < -0.1) ? (u + 0.1) : 0.0);
                }
                Cout[Cbatch * (size_t)b + grow * (size_t)Ccols + gcol] = (CT)y;
            }
        }
    }
}

// ---------------- fp64-accumulating VALU GEMM (round-5 verbatim; weight GEMMs) ----
template <typename BT, typename CT>
__global__ __launch_bounds__(256) void gemm64_k(
    const float* __restrict__ A, size_t Abatch, int lda,
    const BT* __restrict__ Bm, size_t Bbatch, int ldb,
    CT* __restrict__ Cout, size_t Cbatch,
    int K, int Ccols,
    const float* __restrict__ bias,
    const float* __restrict__ S0, size_t Sbatch,
    int addAT, int btrans, int epi) {
    __shared__ float As[32][132];
    __shared__ float AsT[32][132];
    __shared__ BT Bs[32][68];
    __shared__ double degLDS[2][128];
    const int b = blockIdx.z;
    const int i0 = blockIdx.x * 128;
    const int j0 = blockIdx.y * 64;
    const float* Ab = A + Abatch * (size_t)b;
    const BT* Bb = Bm + Bbatch * (size_t)b;
    const int t = threadIdx.x;
    const int wv = t >> 6, ln = t & 63;
    const int ri = (wv >> 1) * 64 + (ln >> 3) * 8;
    const int rj = ((wv & 1) * 8 + (ln & 7)) * 4;

    double acc[8][4];
#pragma unroll
    for (int i = 0; i < 8; ++i)
#pragma unroll
        for (int j = 0; j < 4; ++j) acc[i][j] = 0.0;

    const int a_i = t >> 1, a_m = (t & 1) * 16;
    const int p_m = t >> 3, p_i = (t & 7) * 16;
    const int b_m = t >> 3, b_j = (t & 7) * 8;
    const int w_j = t >> 2, w_m = (t & 3) * 8;
    double degacc = 0.0;

    for (int k0 = 0; k0 < K; k0 += 32) {
        if (k0) __syncthreads();
        {
            const float4* src =
                (const float4*)(Ab + (size_t)(i0 + a_i) * lda + k0 + a_m);
            float4 v0 = src[0], v1 = src[1], v2 = src[2], v3 = src[3];
            if (epi == 2)
                degacc += (((double)v0.x + v0.y) + ((double)v0.z + v0.w)) +
                          (((double)v1.x + v1.y) + ((double)v1.z + v1.w)) +
                          (((double)v2.x + v2.y) + ((double)v2.z + v2.w)) +
                          (((double)v3.x + v3.y) + ((double)v3.z + v3.w));
            As[a_m + 0][a_i] = v0.x;  As[a_m + 1][a_i] = v0.y;
            As[a_m + 2][a_i] = v0.z;  As[a_m + 3][a_i] = v0.w;
            As[a_m + 4][a_i] = v1.x;  As[a_m + 5][a_i] = v1.y;
            As[a_m + 6][a_i] = v1.z;  As[a_m + 7][a_i] = v1.w;
            As[a_m + 8][a_i] = v2.x;  As[a_m + 9][a_i] = v2.y;
            As[a_m + 10][a_i] = v2.z; As[a_m + 11][a_i] = v2.w;
            As[a_m + 12][a_i] = v3.x; As[a_m + 13][a_i] = v3.y;
            As[a_m + 14][a_i] = v3.z; As[a_m + 15][a_i] = v3.w;
        }
        if (addAT) {
            const float4* src =
                (const float4*)(Ab + (size_t)(k0 + p_m) * lda + i0 + p_i);
            float4 v0 = src[0], v1 = src[1], v2 = src[2], v3 = src[3];
            AsT[p_m][p_i + 0] = v0.x;  AsT[p_m][p_i + 1] = v0.y;
            AsT[p_m][p_i + 2] = v0.z;  AsT[p_m][p_i + 3] = v0.w;
            AsT[p_m][p_i + 4] = v1.x;  AsT[p_m][p_i + 5] = v1.y;
            AsT[p_m][p_i + 6] = v1.z;  AsT[p_m][p_i + 7] = v1.w;
            AsT[p_m][p_i + 8] = v2.x;  AsT[p_m][p_i + 9] = v2.y;
            AsT[p_m][p_i + 10] = v2.z; AsT[p_m][p_i + 11] = v2.w;
            AsT[p_m][p_i + 12] = v3.x; AsT[p_m][p_i + 13] = v3.y;
            AsT[p_m][p_i + 14] = v3.z; AsT[p_m][p_i + 15] = v3.w;
        }
        if (!btrans) {
            const BT* src = Bb + (size_t)(k0 + b_m) * ldb + j0 + b_j;
            if constexpr (sizeof(BT) == 8) {
                const double2* s2 = (const double2*)src;
                double2 u0 = s2[0], u1 = s2[1], u2 = s2[2], u3 = s2[3];
                Bs[b_m][b_j + 0] = (BT)u0.x; Bs[b_m][b_j + 1] = (BT)u0.y;
                Bs[b_m][b_j + 2] = (BT)u1.x; Bs[b_m][b_j + 3] = (BT)u1.y;
                Bs[b_m][b_j + 4] = (BT)u2.x; Bs[b_m][b_j + 5] = (BT)u2.y;
                Bs[b_m][b_j + 6] = (BT)u3.x; Bs[b_m][b_j + 7] = (BT)u3.y;
            } else {
                const float4* s4 = (const float4*)src;
                float4 u0 = s4[0], u1 = s4[1];
                Bs[b_m][b_j + 0] = (BT)u0.x; Bs[b_m][b_j + 1] = (BT)u0.y;
                Bs[b_m][b_j + 2] = (BT)u0.z; Bs[b_m][b_j + 3] = (BT)u0.w;
                Bs[b_m][b_j + 4] = (BT)u1.x; Bs[b_m][b_j + 5] = (BT)u1.y;
                Bs[b_m][b_j + 6] = (BT)u1.z; Bs[b_m][b_j + 7] = (BT)u1.w;
            }
        } else {
            const float* Wf = reinterpret_cast<const float*>(Bm);
            const float4* src =
                (const float4*)(Wf + (size_t)(j0 + w_j) * ldb + k0 + w_m);
            float4 v0 = src[0], v1 = src[1];
            Bs[w_m + 0][w_j] = (BT)v0.x; Bs[w_m + 1][w_j] = (BT)v0.y;
            Bs[w_m + 2][w_j] = (BT)v0.z; Bs[w_m + 3][w_j] = (BT)v0.w;
            Bs[w_m + 4][w_j] = (BT)v1.x; Bs[w_m + 5][w_j] = (BT)v1.y;
            Bs[w_m + 6][w_j] = (BT)v1.z; Bs[w_m + 7][w_j] = (BT)v1.w;
        }
        __syncthreads();
#pragma unroll 4
        for (int mk = 0; mk < 32; ++mk) {
            float4 a0 = *(const float4*)&As[mk][ri];
            float4 a1 = *(const float4*)&As[mk][ri + 4];
            double ad[8] = {a0.x, a0.y, a0.z, a0.w, a1.x, a1.y, a1.z, a1.w};
            if (addAT) {
                float4 t0 = *(const float4*)&AsT[mk][ri];
                float4 t1 = *(const float4*)&AsT[mk][ri + 4];
                ad[0] += t0.x; ad[1] += t0.y; ad[2] += t0.z; ad[3] += t0.w;
                ad[4] += t1.x; ad[5] += t1.y; ad[6] += t1.z; ad[7] += t1.w;
            }
            double bd[4];
#pragma unroll
            for (int c = 0; c < 4; ++c) bd[c] = (double)Bs[mk][rj + c];
#pragma unroll
            for (int iy = 0; iy < 8; ++iy)
#pragma unroll
                for (int jx = 0; jx < 4; ++jx)
                    acc[iy][jx] = fma(ad[iy], bd[jx], acc[iy][jx]);
        }
    }

    if (epi == 2) degLDS[t & 1][t >> 1] = degacc;
    __syncthreads();

#pragma unroll
    for (int iy = 0; iy < 8; ++iy) {
        const int row = i0 + ri + iy;
        CT* cp = Cout + Cbatch * (size_t)b + (size_t)row * Ccols + j0 + rj;
        CT o[4];
        if (epi == 0) {
#pragma unroll
            for (int jx = 0; jx < 4; ++jx) o[jx] = (CT)acc[iy][jx];
        } else if (epi == 1) {
#pragma unroll
            for (int jx = 0; jx < 4; ++jx)
                o[jx] = (CT)(acc[iy][jx] + (double)bias[j0 + rj + jx]);
        } else {
            const double dg = degLDS[0][ri + iy] + degLDS[1][ri + iy];
            const double cA = 0.8 - 0.02 * dg;
            const BT* sp = Bb + (size_t)row * ldb + j0 + rj;
            const float* s0p = S0 + Sbatch * (size_t)b + (size_t)row * Ccols + j0 + rj;
#pragma unroll
            for (int jx = 0; jx < 4; ++jx) {
                const double u = cA * (double)sp[jx] + 0.01 * acc[iy][jx] +
                                 0.2 * (double)s0p[jx];
                const double v = (u > 0.1) ? (u - 0.1) : ((u < -0.1) ? (u + 0.1) : 0.0);
                o[jx] = (CT)v;
            }
        }
        if constexpr (sizeof(CT) == 8) {
            double2 q0, q1;
            q0.x = o[0]; q0.y = o[1]; q1.x = o[2]; q1.y = o[3];
            *(double2*)cp = q0;
            *(double2*)(cp + 2) = q1;
        } else {
            *(float4*)cp = make_float4(o[0], o[1], o[2], o[3]);
        }
    }
}

// ---------------- row L2-normalize + relu ----------------
__global__ __launch_bounds__(64) void l2relu_k(float* __restrict__ buf, int F) {
    const size_t row = blockIdx.x;
    float* p = buf + row * (size_t)F;
    double ss = 0.0;
    for (int k = threadIdx.x; k < F; k += 64) {
        const double v = (double)p[k];
        ss += v * v;
    }
#pragma unroll
    for (int o = 32; o; o >>= 1) ss += __shfl_xor(ss, o, 64);
    const double den = fmax(sqrt(ss), 1e-12);
    for (int k = threadIdx.x; k < F; k += 64) {
        const double v = (double)p[k] / den;
        p[k] = (float)(v > 0.0 ? v : 0.0);
    }
}

// ---------------- BatchNorm per node, f64 two-pass ----------------
__global__ __launch_bounds__(256) void bn_k(float* __restrict__ buf,
                                            const float* __restrict__ g,
                                            const float* __restrict__ be, int fl) {
    const int n = blockIdx.x;
    const int F = 1 << fl;
    const int total = NB << fl;
    __shared__ double red[4];
    __shared__ double sh_m, sh_scale, sh_be;
    const int wv = threadIdx.x >> 6, ln = threadIdx.x & 63;
    double s = 0.0;
    for (int idx = threadIdx.x; idx < total; idx += 256) {
        const int bb = idx >> fl, f = idx & (F - 1);
        s += (double)buf[((size_t)bb * NN + n) * F + f];
    }
    s = waveSumD(s);
    if (!ln) red[wv] = s;
    __syncthreads();
    if (!threadIdx.x) sh_m = ((red[0] + red[1]) + (red[2] + red[3])) / (double)total;
    __syncthreads();
    const double m = sh_m;
    double v2 = 0.0;
    for (int idx = threadIdx.x; idx < total; idx += 256) {
        const int bb = idx >> fl, f = idx & (F - 1);
        const double d = (double)buf[((size_t)bb * NN + n) * F + f] - m;
        v2 += d * d;
    }
    v2 = waveSumD(v2);
    __syncthreads();
    if (!ln) red[wv] = v2;
    __syncthreads();
    if (!threadIdx.x) {
        const double var = ((red[0] + red[1]) + (red[2] + red[3])) / (double)total;
        sh_scale = (1.0 / sqrt(var + 1e-5)) * (double)g[n];
        sh_be = (double)be[n];
    }
    __syncthreads();
    const double sc = sh_scale, bb2 = sh_be;
    for (int idx = threadIdx.x; idx < total; idx += 256) {
        const int bb = idx >> fl, f = idx & (F - 1);
        float* pp = &buf[((size_t)bb * NN + n) * F + f];
        *pp = (float)(((double)*pp - m) * sc + bb2);
    }
}

// ---------------- softmax over last dim (512) ----------------
template <typename T>
__global__ __launch_bounds__(256) void softmax_k(const T* __restrict__ in,
                                                 float* __restrict__ out) {
    const size_t row = blockIdx.x;
    const T* p = in + row * (size_t)F2C;
    float* q = out + row * (size_t)F2C;
    const int t = threadIdx.x;
    const int wv = t >> 6, ln = t & 63;
    const double v0 = (double)p[t], v1 = (double)p[t + 256];
    double m = fmax(v0, v1);
#pragma unroll
    for (int o = 32; o; o >>= 1) m = fmax(m, __shfl_xor(m, o, 64));
    __shared__ double red[4];
    if (!ln) red[wv] = m;
    __syncthreads();
    m = fmax(fmax(red[0], red[1]), fmax(red[2], red[3]));
    const double e0 = exp(v0 - m), e1 = exp(v1 - m);
    double s = e0 + e1;
#pragma unroll
    for (int o = 32; o; o >>= 1) s += __shfl_xor(s, o, 64);
    __syncthreads();
    if (!ln) red[wv] = s;
    __syncthreads();
    s = (red[0] + red[1]) + (red[2] + red[3]);
    q[t] = (float)(e0 / s);
    q[t + 256] = (float)(e1 / s);
}

extern "C" void kernel_launch(void* const* d_in, const int* in_sizes, int n_in,
                              void* d_out, int out_size, void* d_ws, size_t ws_size,
                              hipStream_t stream) {
    const float* x = (const float*)d_in[0];
    const float* adj = (const float*)d_in[1];
    const float* W1 = (const float*)d_in[2];
    const float* b1 = (const float*)d_in[3];
    const float* g1 = (const float*)d_in[4];
    const float* be1 = (const float*)d_in[5];
    const float* W2 = (const float*)d_in[6];
    const float* b2 = (const float*)d_in[7];
    const float* g2 = (const float*)d_in[8];
    const float* be2 = (const float*)d_in[9];
    float* out = (float*)d_out;
    float* ws = (float*)d_ws;

    const size_t M2 = (size_t)NB * NN * F2C;     // 8,388,608 floats
    const size_t szAgg = (size_t)NB * NN * F0C;  // 4,194,304 floats

    const int tier = (ws_size >= ((size_t)192 << 20)) ? 0
                   : (ws_size >= ((size_t)64 << 20)) ? 1 : 2;

    if (tier == 0) {
        // [s0F 32MiB][tmpF 32MiB][D1 64MiB][D2 64MiB]; degD in dead tmpF hole.
        float* s0F = ws;
        float* tmpF = ws + M2;
        double* D1 = (double*)(ws + 2 * M2);
        double* D2 = D1 + M2;
        float* aggF = tmpF;                          // 16 MiB
        float* t1F = tmpF + szAgg;                   // 8 MiB at +16 MiB
        float* h2F = tmpF;                           // reuses agg (dead)
        double* degD = (double*)(tmpF + 7340032);    // +28 MiB, 128 KiB

        deg_k<<<NB * NN, 256, 0, stream>>>(adj, degD);
        // 1. agg = adj @ x  (MFMA)
        mf_k<float, float, false, 0><<<dim3(16, 2, 8), 256, 0, stream>>>(
            adj, (size_t)NN * NN, NN, x, (size_t)NN * F0C, F0C,
            aggF, (size_t)NN * F0C, NN, F0C, nullptr, 0, nullptr);
        // 2. t1 = agg @ W1^T + b1  (VALU, proven)
        gemm64_k<float, float><<<dim3(128, 2, 1), 256, 0, stream>>>(
            aggF, 0, F0C, W1, 0, F0C, t1F, 0, F0C, F1C, b1, nullptr, 0, 0, 1, 1);
        l2relu_k<<<NB * NN, 64, 0, stream>>>(t1F, F1C);
        bn_k<<<NN, 256, 0, stream>>>(t1F, g1, be1, 7);
        // 3. h2 = adj @ t1  (MFMA)
        mf_k<float, float, false, 0><<<dim3(16, 1, 8), 256, 0, stream>>>(
            adj, (size_t)NN * NN, NN, t1F, (size_t)NN * F1C, F1C,
            h2F, (size_t)NN * F1C, NN, F1C, nullptr, 0, nullptr);
        // 4. s0 = h2 @ W2^T + b2  (VALU, proven)
        gemm64_k<float, float><<<dim3(128, 8, 1), 256, 0, stream>>>(
            h2F, 0, F1C, W2, 0, F1C, s0F, 0, F1C, F2C, b2, nullptr, 0, 0, 1, 1);
        l2relu_k<<<NB * NN, 64, 0, stream>>>(s0F, F2C);
        bn_k<<<NN, 256, 0, stream>>>(s0F, g2, be2, 9);
        // 5. prox x10 (MFMA dbuf, f64 state): s0F -> D1; ping-pong; it9 -> D2
        mf_k<float, double, true, 2><<<dim3(16, 4, 8), 256, 0, stream>>>(
            adj, (size_t)NN * NN, NN, s0F, (size_t)NN * F2C, F2C,
            D1, (size_t)NN * F2C, NN, F2C, s0F, (size_t)NN * F2C, degD);
        const double* Sin = D1;
        for (int it = 1; it < 10; ++it) {
            double* Sout = (it & 1) ? D2 : D1;
            mf_k<double, double, true, 2><<<dim3(16, 4, 8), 256, 0, stream>>>(
                adj, (size_t)NN * NN, NN, Sin, (size_t)NN * F2C, F2C,
                Sout, (size_t)NN * F2C, NN, F2C, s0F, (size_t)NN * F2C, degD);
            Sin = Sout;
        }
        softmax_k<double><<<NB * NN, 256, 0, stream>>>(D2, out);
    } else if (tier == 1) {
        float* R0 = ws;
        float* R1 = ws + M2;
        float* aggF = R1;
        float* t1F = R0;
        float* h2F = R1;
        float* s0F = R0;

        gemm64_k<float, float><<<dim3(16, 4, 8), 256, 0, stream>>>(
            adj, (size_t)NN * NN, NN, x, (size_t)NN * F0C, F0C,
            aggF, (size_t)NN * F0C, NN, F0C, nullptr, nullptr, 0, 0, 0, 0);
        gemm64_k<float, float><<<dim3(128, 2, 1), 256, 0, stream>>>(
            aggF, 0, F0C, W1, 0, F0C, t1F, 0, F0C, F1C, b1, nullptr, 0, 0, 1, 1);
        l2relu_k<<<NB * NN, 64, 0, stream>>>(t1F, F1C);
        bn_k<<<NN, 256, 0, stream>>>(t1F, g1, be1, 7);
        gemm64_k<float, float><<<dim3(16, 2, 8), 256, 0, stream>>>(
            adj, (size_t)NN * NN, NN, t1F, (size_t)NN * F1C, F1C,
            h2F, (size_t)NN * F1C, NN, F1C, nullptr, nullptr, 0, 0, 0, 0);
        gemm64_k<float, float><<<dim3(128, 8, 1), 256, 0, stream>>>(
            h2F, 0, F1C, W2, 0, F1C, s0F, 0, F1C, F2C, b2, nullptr, 0, 0, 1, 1);
        l2relu_k<<<NB * NN, 64, 0, stream>>>(s0F, F2C);
        bn_k<<<NN, 256, 0, stream>>>(s0F, g2, be2, 9);
        const float* Sin = s0F;
        for (int it = 0; it < 10; ++it) {
            float* Sout = (it & 1) ? out : R1;
            gemm64_k<float, float><<<dim3(16, 8, 8), 256, 0, stream>>>(
                adj, (size_t)NN * NN, NN, Sin, (size_t)NN * F2C, F2C,
                Sout, (size_t)NN * F2C, NN, F2C, nullptr, s0F, (size_t)NN * F2C, 1, 0, 2);
            Sin = Sout;
        }
        softmax_k<float><<<NB * NN, 256, 0, stream>>>(out, out);
    } else {
        float* Wp0 = ws;
        float* Wp1 = ws + (size_t)NN * F2C;
        float* xW1 = ws;
        float* t1 = out;
        float* h2 = ws;
        float* s0 = out;

        gemm64_k<float, float><<<dim3(128, 2, 1), 256, 0, stream>>>(
            x, 0, F0C, W1, 0, F0C, xW1, 0, F0C, F1C, nullptr, nullptr, 0, 0, 1, 0);
        gemm64_k<float, float><<<dim3(16, 2, 8), 256, 0, stream>>>(
            adj, (size_t)NN * NN, NN, xW1, (size_t)NN * F1C, F1C,
            t1, (size_t)NN * F1C, NN, F1C, b1, nullptr, 0, 0, 0, 1);
        l2relu_k<<<NB * NN, 64, 0, stream>>>(t1, F1C);
        bn_k<<<NN, 256, 0, stream>>>(t1, g1, be1, 7);
        gemm64_k<float, float><<<dim3(16, 2, 8), 256, 0, stream>>>(
            adj, (size_t)NN * NN, NN, t1, (size_t)NN * F1C, F1C,
            h2, (size_t)NN * F1C, NN, F1C, nullptr, nullptr, 0, 0, 0, 0);
        gemm64_k<float, float><<<dim3(128, 8, 1), 256, 0, stream>>>(
            h2, 0, F1C, W2, 0, F1C, s0, 0, F1C, F2C, b2, nullptr, 0, 0, 1, 1);
        l2relu_k<<<NB * NN, 64, 0, stream>>>(s0, F2C);
        bn_k<<<NN, 256, 0, stream>>>(s0, g2, be2, 9);
        for (int b = 0; b < NB; ++b) {
            float* s0b = out + (size_t)b * NN * F2C;
            const float* Ab = adj + (size_t)b * NN * NN;
            const float* Sin = s0b;
            for (int it = 0; it < 10; ++it) {
                float* Sout = (it == 9) ? s0b : ((it & 1) ? Wp1 : Wp0);
                gemm64_k<float, float><<<dim3(16, 8, 1), 256, 0, stream>>>(
                    Ab, 0, NN, Sin, 0, F2C,
                    Sout, 0, NN, F2C, nullptr, s0b, 0, 1, 0, 2);
                Sin = Sout;
            }
        }
        softmax_k<float><<<NB * NN, 256, 0, stream>>>(out, out);
    }
}

// Round 13
// 6259.787 us; speedup vs baseline: 1.2966x; 1.0061x over previous
//
#include <hip/hip_runtime.h>
#include <cstdint>
#include <cstddef>

#define NN 2048
#define NB 8
#define F0C 256
#define F1C 128
#define F2C 512

typedef double f64x4 __attribute__((ext_vector_type(4)));

// ---------------- helpers ----------------
__device__ __forceinline__ double waveSumD(double v) {
#pragma unroll
    for (int o = 32; o; o >>= 1) v += __shfl_down(v, o, 64);
    return v;
}

// ---------------- deg[row] = f64 rowsum of adj row ----------------
__global__ __launch_bounds__(256) void deg_k(const float* __restrict__ adj,
                                             double* __restrict__ degD) {
    const size_t row = blockIdx.x;
    const float4* r4 = (const float4*)(adj + row * (size_t)NN);
    float4 a = r4[threadIdx.x];
    float4 b = r4[threadIdx.x + 256];
    double s = (((double)a.x + a.y) + ((double)a.z + a.w)) +
               (((double)b.x + b.y) + ((double)b.z + b.w));
    s = waveSumD(s);
    __shared__ double red[4];
    if (!(threadIdx.x & 63)) red[threadIdx.x >> 6] = s;
    __syncthreads();
    if (!threadIdx.x) degD[row] = (red[0] + red[1]) + (red[2] + red[3]);
}

// ---------------- f64 MFMA GEMM: dbuf + full-step-hoisted loads + raw barrier ----
// mode-3 mapping (HW-verified r8):
//   A: lane l holds A[row=l&15][k=l>>4]
//   B: lane l holds B[k=l>>4][col=l&15]
//   D: lane l, reg v holds D[row=(l>>4)+4*v][col=l&15]
// r12 lesson: __syncthreads() drains vmcnt(0) -> deep prefetch impossible; and
// STORE had only half-step latency cover. New schedule (T14+T4):
//   prologue: LOAD(0) STORE(0) LOAD(1) BAR
//   loop:     COMP(0,0) STORE(1) LOAD(k+2) COMP(0,1) BAR
//             COMP(1,0) STORE(0) LOAD(k+3) COMP(1,1) BAR
// BAR = s_waitcnt lgkmcnt(0) + raw s_barrier (+sched_barrier pin, rule #18) —
// in-flight global loads survive the barrier; each STORE's vmcnt wait has a
// full k-step + barrier of cover. Buffer safety: STORE(b) always overwrites the
// buffer whose last readers completed before the PREVIOUS barrier (lgkmcnt-drained).
// Staging in NAMED registers (r10 lesson: arrays/lambdas -> scratch spill).
template <typename BT, typename CT, bool ADD_AT, int EPI>
__global__ __launch_bounds__(256, 2) void mf_k(
    const float* __restrict__ A, size_t Abatch, int lda,
    const BT* __restrict__ Bm, size_t Bbatch, int ldb,
    CT* __restrict__ Cout, size_t Cbatch, int K, int Ccols,
    const float* __restrict__ S0, size_t Sbatch,
    const double* __restrict__ degD) {
    __shared__ float As[2][128][20];                  // [buf][i][k]
    __shared__ float AsT[2][ADD_AT ? 16 : 1][136];    // [buf][k][i]
    __shared__ BT Bs[2][16][132];                     // [buf][k][j]
    __shared__ double degL[EPI == 2 ? 128 : 1];

    const int b = blockIdx.z;
    const int i0 = blockIdx.x * 128;
    const int j0 = blockIdx.y * 128;
    const float* Ab = A + Abatch * (size_t)b;
    const BT* Bb = Bm + Bbatch * (size_t)b;
    const int t = threadIdx.x;
    const int l = t & 63;
    const int wv = t >> 6;
    const int wr = (wv >> 1) * 64;   // wave row base in tile
    const int wc = (wv & 1) * 64;    // wave col base in tile
    const int lr = l & 15;           // A-row / B-col / D-col lane index
    const int lk = l >> 4;           // k lane index (0..3); D rows = lk + 4v

    // staging indices
    const int sa_i = t >> 2, sa_q = (t & 3) * 4;   // A: rows sa_i, sa_i+64; cols sa_q..+3
    const int sb_k = t >> 5, sb_c = (t & 31) * 4;  // AT/B: rows sb_k, sb_k+8; cols sb_c..+3

    // staging registers — individually named (never address-taken)
    float4 aR0, aR1;
    float4 tR0, tR1;
    double2 bD0, bD1, bD2, bD3;
    float4 bF0, bF1;

#define MF_LOAD(K0)                                                              \
    {                                                                            \
        const int _k0 = (K0);                                                    \
        aR0 = *(const float4*)(Ab + (size_t)(i0 + sa_i) * lda + _k0 + sa_q);     \
        aR1 = *(const float4*)(Ab + (size_t)(i0 + sa_i + 64) * lda + _k0 + sa_q);\
        if constexpr (ADD_AT) {                                                  \
            tR0 = *(const float4*)(Ab + (size_t)(_k0 + sb_k) * lda + i0 + sb_c); \
            tR1 = *(const float4*)(Ab + (size_t)(_k0 + sb_k + 8) * lda + i0 + sb_c);\
        }                                                                        \
        if constexpr (sizeof(BT) == 8) {                                         \
            const BT* _s0 = Bb + (size_t)(_k0 + sb_k) * ldb + j0 + sb_c;         \
            const BT* _s1 = Bb + (size_t)(_k0 + sb_k + 8) * ldb + j0 + sb_c;     \
            bD0 = *(const double2*)_s0; bD1 = *(const double2*)(_s0 + 2);        \
            bD2 = *(const double2*)_s1; bD3 = *(const double2*)(_s1 + 2);        \
        } else {                                                                 \
            bF0 = *(const float4*)(Bb + (size_t)(_k0 + sb_k) * ldb + j0 + sb_c); \
            bF1 = *(const float4*)(Bb + (size_t)(_k0 + sb_k + 8) * ldb + j0 + sb_c);\
        }                                                                        \
    }

#define MF_STORE(BF)                                                             \
    {                                                                            \
        *(float4*)&As[BF][sa_i][sa_q] = aR0;                                     \
        *(float4*)&As[BF][sa_i + 64][sa_q] = aR1;                                \
        if constexpr (ADD_AT) {                                                  \
            *(float4*)&AsT[BF][sb_k][sb_c] = tR0;                                \
            *(float4*)&AsT[BF][sb_k + 8][sb_c] = tR1;                            \
        }                                                                        \
        if constexpr (sizeof(BT) == 8) {                                         \
            *(double2*)&Bs[BF][sb_k][sb_c] = bD0;                                \
            *(double2*)&Bs[BF][sb_k][sb_c + 2] = bD1;                            \
            *(double2*)&Bs[BF][sb_k + 8][sb_c] = bD2;                            \
            *(double2*)&Bs[BF][sb_k + 8][sb_c + 2] = bD3;                        \
        } else {                                                                 \
            *(float4*)&Bs[BF][sb_k][sb_c] = bF0;                                 \
            *(float4*)&Bs[BF][sb_k + 8][sb_c] = bF1;                             \
        }                                                                        \
    }

// raw barrier: LDS-only drain, global loads stay in flight (T4); pin per rule #18
#define MF_BAR()                                                                 \
    {                                                                            \
        asm volatile("s_waitcnt lgkmcnt(0)" ::: "memory");                       \
        __builtin_amdgcn_s_barrier();                                            \
        __builtin_amdgcn_sched_barrier(0);                                       \
    }

// one half of a k-step: kk = 2H, 2H+1 (32 MFMAs), wrapped in setprio
#define MF_COMP_HALF(CUR, H)                                                     \
    {                                                                            \
        __builtin_amdgcn_s_setprio(1);                                           \
        _Pragma("unroll")                                                        \
        for (int kk = 2 * (H); kk < 2 * (H) + 2; ++kk) {                         \
            const int kr = kk * 4 + lk;                                          \
            double av[4], bv[4];                                                 \
            _Pragma("unroll")                                                    \
            for (int r = 0; r < 4; ++r) {                                        \
                const int ii = wr + r * 16 + lr;                                 \
                double a = (double)As[CUR][ii][kr];                              \
                if constexpr (ADD_AT) a += (double)AsT[CUR][kr][ii];             \
                av[r] = a;                                                       \
            }                                                                    \
            _Pragma("unroll")                                                    \
            for (int c = 0; c < 4; ++c)                                          \
                bv[c] = (double)Bs[CUR][kr][wc + c * 16 + lr];                   \
            _Pragma("unroll")                                                    \
            for (int r = 0; r < 4; ++r)                                          \
                _Pragma("unroll")                                                \
                for (int c = 0; c < 4; ++c)                                      \
                    acc[r][c] = __builtin_amdgcn_mfma_f64_16x16x4f64(            \
                        av[r], bv[c], acc[r][c], 0, 0, 0);                       \
        }                                                                        \
        __builtin_amdgcn_s_setprio(0);                                           \
    }

    f64x4 acc[4][4];
#pragma unroll
    for (int r = 0; r < 4; ++r)
#pragma unroll
        for (int c = 0; c < 4; ++c)
#pragma unroll
            for (int v = 0; v < 4; ++v) acc[r][c][v] = 0.0;

    if (EPI == 2) {
        if (t < 128) degL[t] = degD[(size_t)b * NN + i0 + t];
    }

    const int nk = K / 16;  // even at all call sites (128 / 16 / 8)
    // prologue: tile0 staged; tile1 loads in flight across the barrier
    MF_LOAD(0);
    MF_STORE(0);
    MF_LOAD(16);
    MF_BAR();

    for (int ks = 0; ks < nk; ks += 2) {
        MF_COMP_HALF(0, 0);
        MF_STORE(1);                          // consumes LOAD(ks+1): full-step cover
        if (ks + 2 < nk) MF_LOAD((ks + 2) * 16);
        MF_COMP_HALF(0, 1);
        MF_BAR();
        MF_COMP_HALF(1, 0);
        if (ks + 2 < nk) MF_STORE(0);         // consumes LOAD(ks+2)
        if (ks + 3 < nk) MF_LOAD((ks + 3) * 16);
        MF_COMP_HALF(1, 1);
        if (ks + 2 < nk) MF_BAR();
    }
#undef MF_LOAD
#undef MF_STORE
#undef MF_BAR
#undef MF_COMP_HALF

    // epilogue (D: row = lk + 4v, col = lr)
#pragma unroll
    for (int r = 0; r < 4; ++r) {
#pragma unroll
        for (int v = 0; v < 4; ++v) {
            const int rl = wr + r * 16 + lk + 4 * v;
            const size_t grow = (size_t)(i0 + rl);
            double cA = 0.0;
            if (EPI == 2) cA = 0.8 - 0.02 * degL[rl];
#pragma unroll
            for (int c = 0; c < 4; ++c) {
                const int gcol = j0 + wc + c * 16 + lr;
                double y = acc[r][c][v];
                if (EPI == 2) {
                    const double sv = (double)Bb[grow * (size_t)ldb + gcol];
                    const double s0v =
                        (double)S0[Sbatch * (size_t)b + grow * (size_t)Ccols + gcol];
                    const double u = cA * sv + 0.01 * y + 0.2 * s0v;
                    y = (u > 0.1) ? (u - 0.1) : ((u < -0.1) ? (u + 0.1) : 0.0);
                }
                Cout[Cbatch * (size_t)b + grow * (size_t)Ccols + gcol] = (CT)y;
            }
        }
    }
}

// ---------------- fp64-accumulating VALU GEMM (round-5 verbatim; weight GEMMs) ----
template <typename BT, typename CT>
__global__ __launch_bounds__(256) void gemm64_k(
    const float* __restrict__ A, size_t Abatch, int lda,
    const BT* __restrict__ Bm, size_t Bbatch, int ldb,
    CT* __restrict__ Cout, size_t Cbatch,
    int K, int Ccols,
    const float* __restrict__ bias,
    const float* __restrict__ S0, size_t Sbatch,
    int addAT, int btrans, int epi) {
    __shared__ float As[32][132];
    __shared__ float AsT[32][132];
    __shared__ BT Bs[32][68];
    __shared__ double degLDS[2][128];
    const int b = blockIdx.z;
    const int i0 = blockIdx.x * 128;
    const int j0 = blockIdx.y * 64;
    const float* Ab = A + Abatch * (size_t)b;
    const BT* Bb = Bm + Bbatch * (size_t)b;
    const int t = threadIdx.x;
    const int wv = t >> 6, ln = t & 63;
    const int ri = (wv >> 1) * 64 + (ln >> 3) * 8;
    const int rj = ((wv & 1) * 8 + (ln & 7)) * 4;

    double acc[8][4];
#pragma unroll
    for (int i = 0; i < 8; ++i)
#pragma unroll
        for (int j = 0; j < 4; ++j) acc[i][j] = 0.0;

    const int a_i = t >> 1, a_m = (t & 1) * 16;
    const int p_m = t >> 3, p_i = (t & 7) * 16;
    const int b_m = t >> 3, b_j = (t & 7) * 8;
    const int w_j = t >> 2, w_m = (t & 3) * 8;
    double degacc = 0.0;

    for (int k0 = 0; k0 < K; k0 += 32) {
        if (k0) __syncthreads();
        {
            const float4* src =
                (const float4*)(Ab + (size_t)(i0 + a_i) * lda + k0 + a_m);
            float4 v0 = src[0], v1 = src[1], v2 = src[2], v3 = src[3];
            if (epi == 2)
                degacc += (((double)v0.x + v0.y) + ((double)v0.z + v0.w)) +
                          (((double)v1.x + v1.y) + ((double)v1.z + v1.w)) +
                          (((double)v2.x + v2.y) + ((double)v2.z + v2.w)) +
                          (((double)v3.x + v3.y) + ((double)v3.z + v3.w));
            As[a_m + 0][a_i] = v0.x;  As[a_m + 1][a_i] = v0.y;
            As[a_m + 2][a_i] = v0.z;  As[a_m + 3][a_i] = v0.w;
            As[a_m + 4][a_i] = v1.x;  As[a_m + 5][a_i] = v1.y;
            As[a_m + 6][a_i] = v1.z;  As[a_m + 7][a_i] = v1.w;
            As[a_m + 8][a_i] = v2.x;  As[a_m + 9][a_i] = v2.y;
            As[a_m + 10][a_i] = v2.z; As[a_m + 11][a_i] = v2.w;
            As[a_m + 12][a_i] = v3.x; As[a_m + 13][a_i] = v3.y;
            As[a_m + 14][a_i] = v3.z; As[a_m + 15][a_i] = v3.w;
        }
        if (addAT) {
            const float4* src =
                (const float4*)(Ab + (size_t)(k0 + p_m) * lda + i0 + p_i);
            float4 v0 = src[0], v1 = src[1], v2 = src[2], v3 = src[3];
            AsT[p_m][p_i + 0] = v0.x;  AsT[p_m][p_i + 1] = v0.y;
            AsT[p_m][p_i + 2] = v0.z;  AsT[p_m][p_i + 3] = v0.w;
            AsT[p_m][p_i + 4] = v1.x;  AsT[p_m][p_i + 5] = v1.y;
            AsT[p_m][p_i + 6] = v1.z;  AsT[p_m][p_i + 7] = v1.w;
            AsT[p_m][p_i + 8] = v2.x;  AsT[p_m][p_i + 9] = v2.y;
            AsT[p_m][p_i + 10] = v2.z; AsT[p_m][p_i + 11] = v2.w;
            AsT[p_m][p_i + 12] = v3.x; AsT[p_m][p_i + 13] = v3.y;
            AsT[p_m][p_i + 14] = v3.z; AsT[p_m][p_i + 15] = v3.w;
        }
        if (!btrans) {
            const BT* src = Bb + (size_t)(k0 + b_m) * ldb + j0 + b_j;
            if constexpr (sizeof(BT) == 8) {
                const double2* s2 = (const double2*)src;
                double2 u0 = s2[0], u1 = s2[1], u2 = s2[2], u3 = s2[3];
                Bs[b_m][b_j + 0] = (BT)u0.x; Bs[b_m][b_j + 1] = (BT)u0.y;
                Bs[b_m][b_j + 2] = (BT)u1.x; Bs[b_m][b_j + 3] = (BT)u1.y;
                Bs[b_m][b_j + 4] = (BT)u2.x; Bs[b_m][b_j + 5] = (BT)u2.y;
                Bs[b_m][b_j + 6] = (BT)u3.x; Bs[b_m][b_j + 7] = (BT)u3.y;
            } else {
                const float4* s4 = (const float4*)src;
                float4 u0 = s4[0], u1 = s4[1];
                Bs[b_m][b_j + 0] = (BT)u0.x; Bs[b_m][b_j + 1] = (BT)u0.y;
                Bs[b_m][b_j + 2] = (BT)u0.z; Bs[b_m][b_j + 3] = (BT)u0.w;
                Bs[b_m][b_j + 4] = (BT)u1.x; Bs[b_m][b_j + 5] = (BT)u1.y;
                Bs[b_m][b_j + 6] = (BT)u1.z; Bs[b_m][b_j + 7] = (BT)u1.w;
            }
        } else {
            const float* Wf = reinterpret_cast<const float*>(Bm);
            const float4* src =
                (const float4*)(Wf + (size_t)(j0 + w_j) * ldb + k0 + w_m);
            float4 v0 = src[0], v1 = src[1];
            Bs[w_m + 0][w_j] = (BT)v0.x; Bs[w_m + 1][w_j] = (BT)v0.y;
            Bs[w_m + 2][w_j] = (BT)v0.z; Bs[w_m + 3][w_j] = (BT)v0.w;
            Bs[w_m + 4][w_j] = (BT)v1.x; Bs[w_m + 5][w_j] = (BT)v1.y;
            Bs[w_m + 6][w_j] = (BT)v1.z; Bs[w_m + 7][w_j] = (BT)v1.w;
        }
        __syncthreads();
#pragma unroll 4
        for (int mk = 0; mk < 32; ++mk) {
            float4 a0 = *(const float4*)&As[mk][ri];
            float4 a1 = *(const float4*)&As[mk][ri + 4];
            double ad[8] = {a0.x, a0.y, a0.z, a0.w, a1.x, a1.y, a1.z, a1.w};
            if (addAT) {
                float4 t0 = *(const float4*)&AsT[mk][ri];
                float4 t1 = *(const float4*)&AsT[mk][ri + 4];
                ad[0] += t0.x; ad[1] += t0.y; ad[2] += t0.z; ad[3] += t0.w;
                ad[4] += t1.x; ad[5] += t1.y; ad[6] += t1.z; ad[7] += t1.w;
            }
            double bd[4];
#pragma unroll
            for (int c = 0; c < 4; ++c) bd[c] = (double)Bs[mk][rj + c];
#pragma unroll
            for (int iy = 0; iy < 8; ++iy)
#pragma unroll
                for (int jx = 0; jx < 4; ++jx)
                    acc[iy][jx] = fma(ad[iy], bd[jx], acc[iy][jx]);
        }
    }

    if (epi == 2) degLDS[t & 1][t >> 1] = degacc;
    __syncthreads();

#pragma unroll
    for (int iy = 0; iy < 8; ++iy) {
        const int row = i0 + ri + iy;
        CT* cp = Cout + Cbatch * (size_t)b + (size_t)row * Ccols + j0 + rj;
        CT o[4];
        if (epi == 0) {
#pragma unroll
            for (int jx = 0; jx < 4; ++jx) o[jx] = (CT)acc[iy][jx];
        } else if (epi == 1) {
#pragma unroll
            for (int jx = 0; jx < 4; ++jx)
                o[jx] = (CT)(acc[iy][jx] + (double)bias[j0 + rj + jx]);
        } else {
            const double dg = degLDS[0][ri + iy] + degLDS[1][ri + iy];
            const double cA = 0.8 - 0.02 * dg;
            const BT* sp = Bb + (size_t)row * ldb + j0 + rj;
            const float* s0p = S0 + Sbatch * (size_t)b + (size_t)row * Ccols + j0 + rj;
#pragma unroll
            for (int jx = 0; jx < 4; ++jx) {
                const double u = cA * (double)sp[jx] + 0.01 * acc[iy][jx] +
                                 0.2 * (double)s0p[jx];
                const double v = (u > 0.1) ? (u - 0.1) : ((u < -0.1) ? (u + 0.1) : 0.0);
                o[jx] = (CT)v;
            }
        }
        if constexpr (sizeof(CT) == 8) {
            double2 q0, q1;
            q0.x = o[0]; q0.y = o[1]; q1.x = o[2]; q1.y = o[3];
            *(double2*)cp = q0;
            *(double2*)(cp + 2) = q1;
        } else {
            *(float4*)cp = make_float4(o[0], o[1], o[2], o[3]);
        }
    }
}

// ---------------- row L2-normalize + relu ----------------
__global__ __launch_bounds__(64) void l2relu_k(float* __restrict__ buf, int F) {
    const size_t row = blockIdx.x;
    float* p = buf + row * (size_t)F;
    double ss = 0.0;
    for (int k = threadIdx.x; k < F; k += 64) {
        const double v = (double)p[k];
        ss += v * v;
    }
#pragma unroll
    for (int o = 32; o; o >>= 1) ss += __shfl_xor(ss, o, 64);
    const double den = fmax(sqrt(ss), 1e-12);
    for (int k = threadIdx.x; k < F; k += 64) {
        const double v = (double)p[k] / den;
        p[k] = (float)(v > 0.0 ? v : 0.0);
    }
}

// ---------------- BatchNorm per node, f64 two-pass ----------------
__global__ __launch_bounds__(256) void bn_k(float* __restrict__ buf,
                                            const float* __restrict__ g,
                                            const float* __restrict__ be, int fl) {
    const int n = blockIdx.x;
    const int F = 1 << fl;
    const int total = NB << fl;
    __shared__ double red[4];
    __shared__ double sh_m, sh_scale, sh_be;
    const int wv = threadIdx.x >> 6, ln = threadIdx.x & 63;
    double s = 0.0;
    for (int idx = threadIdx.x; idx < total; idx += 256) {
        const int bb = idx >> fl, f = idx & (F - 1);
        s += (double)buf[((size_t)bb * NN + n) * F + f];
    }
    s = waveSumD(s);
    if (!ln) red[wv] = s;
    __syncthreads();
    if (!threadIdx.x) sh_m = ((red[0] + red[1]) + (red[2] + red[3])) / (double)total;
    __syncthreads();
    const double m = sh_m;
    double v2 = 0.0;
    for (int idx = threadIdx.x; idx < total; idx += 256) {
        const int bb = idx >> fl, f = idx & (F - 1);
        const double d = (double)buf[((size_t)bb * NN + n) * F + f] - m;
        v2 += d * d;
    }
    v2 = waveSumD(v2);
    __syncthreads();
    if (!ln) red[wv] = v2;
    __syncthreads();
    if (!threadIdx.x) {
        const double var = ((red[0] + red[1]) + (red[2] + red[3])) / (double)total;
        sh_scale = (1.0 / sqrt(var + 1e-5)) * (double)g[n];
        sh_be = (double)be[n];
    }
    __syncthreads();
    const double sc = sh_scale, bb2 = sh_be;
    for (int idx = threadIdx.x; idx < total; idx += 256) {
        const int bb = idx >> fl, f = idx & (F - 1);
        float* pp = &buf[((size_t)bb * NN + n) * F + f];
        *pp = (float)(((double)*pp - m) * sc + bb2);
    }
}

// ---------------- softmax over last dim (512) ----------------
template <typename T>
__global__ __launch_bounds__(256) void softmax_k(const T* __restrict__ in,
                                                 float* __restrict__ out) {
    const size_t row = blockIdx.x;
    const T* p = in + row * (size_t)F2C;
    float* q = out + row * (size_t)F2C;
    const int t = threadIdx.x;
    const int wv = t >> 6, ln = t & 63;
    const double v0 = (double)p[t], v1 = (double)p[t + 256];
    double m = fmax(v0, v1);
#pragma unroll
    for (int o = 32; o; o >>= 1) m = fmax(m, __shfl_xor(m, o, 64));
    __shared__ double red[4];
    if (!ln) red[wv] = m;
    __syncthreads();
    m = fmax(fmax(red[0], red[1]), fmax(red[2], red[3]));
    const double e0 = exp(v0 - m), e1 = exp(v1 - m);
    double s = e0 + e1;
#pragma unroll
    for (int o = 32; o; o >>= 1) s += __shfl_xor(s, o, 64);
    __syncthreads();
    if (!ln) red[wv] = s;
    __syncthreads();
    s = (red[0] + red[1]) + (red[2] + red[3]);
    q[t] = (float)(e0 / s);
    q[t + 256] = (float)(e1 / s);
}

extern "C" void kernel_launch(void* const* d_in, const int* in_sizes, int n_in,
                              void* d_out, int out_size, void* d_ws, size_t ws_size,
                              hipStream_t stream) {
    const float* x = (const float*)d_in[0];
    const float* adj = (const float*)d_in[1];
    const float* W1 = (const float*)d_in[2];
    const float* b1 = (const float*)d_in[3];
    const float* g1 = (const float*)d_in[4];
    const float* be1 = (const float*)d_in[5];
    const float* W2 = (const float*)d_in[6];
    const float* b2 = (const float*)d_in[7];
    const float* g2 = (const float*)d_in[8];
    const float* be2 = (const float*)d_in[9];
    float* out = (float*)d_out;
    float* ws = (float*)d_ws;

    const size_t M2 = (size_t)NB * NN * F2C;     // 8,388,608 floats
    const size_t szAgg = (size_t)NB * NN * F0C;  // 4,194,304 floats

    const int tier = (ws_size >= ((size_t)192 << 20)) ? 0
                   : (ws_size >= ((size_t)64 << 20)) ? 1 : 2;

    if (tier == 0) {
        // [s0F 32MiB][tmpF 32MiB][D1 64MiB][D2 64MiB]; degD in dead tmpF hole.
        float* s0F = ws;
        float* tmpF = ws + M2;
        double* D1 = (double*)(ws + 2 * M2);
        double* D2 = D1 + M2;
        float* aggF = tmpF;                          // 16 MiB
        float* t1F = tmpF + szAgg;                   // 8 MiB at +16 MiB
        float* h2F = tmpF;                           // reuses agg (dead)
        double* degD = (double*)(tmpF + 7340032);    // +28 MiB, 128 KiB

        deg_k<<<NB * NN, 256, 0, stream>>>(adj, degD);
        // 1. agg = adj @ x  (MFMA)
        mf_k<float, float, false, 0><<<dim3(16, 2, 8), 256, 0, stream>>>(
            adj, (size_t)NN * NN, NN, x, (size_t)NN * F0C, F0C,
            aggF, (size_t)NN * F0C, NN, F0C, nullptr, 0, nullptr);
        // 2. t1 = agg @ W1^T + b1  (VALU, proven)
        gemm64_k<float, float><<<dim3(128, 2, 1), 256, 0, stream>>>(
            aggF, 0, F0C, W1, 0, F0C, t1F, 0, F0C, F1C, b1, nullptr, 0, 0, 1, 1);
        l2relu_k<<<NB * NN, 64, 0, stream>>>(t1F, F1C);
        bn_k<<<NN, 256, 0, stream>>>(t1F, g1, be1, 7);
        // 3. h2 = adj @ t1  (MFMA)
        mf_k<float, float, false, 0><<<dim3(16, 1, 8), 256, 0, stream>>>(
            adj, (size_t)NN * NN, NN, t1F, (size_t)NN * F1C, F1C,
            h2F, (size_t)NN * F1C, NN, F1C, nullptr, 0, nullptr);
        // 4. s0 = h2 @ W2^T + b2  (VALU, proven)
        gemm64_k<float, float><<<dim3(128, 8, 1), 256, 0, stream>>>(
            h2F, 0, F1C, W2, 0, F1C, s0F, 0, F1C, F2C, b2, nullptr, 0, 0, 1, 1);
        l2relu_k<<<NB * NN, 64, 0, stream>>>(s0F, F2C);
        bn_k<<<NN, 256, 0, stream>>>(s0F, g2, be2, 9);
        // 5. prox x10 (MFMA dbuf, f64 state): s0F -> D1; ping-pong; it9 -> D2
        mf_k<float, double, true, 2><<<dim3(16, 4, 8), 256, 0, stream>>>(
            adj, (size_t)NN * NN, NN, s0F, (size_t)NN * F2C, F2C,
            D1, (size_t)NN * F2C, NN, F2C, s0F, (size_t)NN * F2C, degD);
        const double* Sin = D1;
        for (int it = 1; it < 10; ++it) {
            double* Sout = (it & 1) ? D2 : D1;
            mf_k<double, double, true, 2><<<dim3(16, 4, 8), 256, 0, stream>>>(
                adj, (size_t)NN * NN, NN, Sin, (size_t)NN * F2C, F2C,
                Sout, (size_t)NN * F2C, NN, F2C, s0F, (size_t)NN * F2C, degD);
            Sin = Sout;
        }
        softmax_k<double><<<NB * NN, 256, 0, stream>>>(D2, out);
    } else if (tier == 1) {
        float* R0 = ws;
        float* R1 = ws + M2;
        float* aggF = R1;
        float* t1F = R0;
        float* h2F = R1;
        float* s0F = R0;

        gemm64_k<float, float><<<dim3(16, 4, 8), 256, 0, stream>>>(
            adj, (size_t)NN * NN, NN, x, (size_t)NN * F0C, F0C,
            aggF, (size_t)NN * F0C, NN, F0C, nullptr, nullptr, 0, 0, 0, 0);
        gemm64_k<float, float><<<dim3(128, 2, 1), 256, 0, stream>>>(
            aggF, 0, F0C, W1, 0, F0C, t1F, 0, F0C, F1C, b1, nullptr, 0, 0, 1, 1);
        l2relu_k<<<NB * NN, 64, 0, stream>>>(t1F, F1C);
        bn_k<<<NN, 256, 0, stream>>>(t1F, g1, be1, 7);
        gemm64_k<float, float><<<dim3(16, 2, 8), 256, 0, stream>>>(
            adj, (size_t)NN * NN, NN, t1F, (size_t)NN * F1C, F1C,
            h2F, (size_t)NN * F1C, NN, F1C, nullptr, nullptr, 0, 0, 0, 0);
        gemm64_k<float, float><<<dim3(128, 8, 1), 256, 0, stream>>>(
            h2F, 0, F1C, W2, 0, F1C, s0F, 0, F1C, F2C, b2, nullptr, 0, 0, 1, 1);
        l2relu_k<<<NB * NN, 64, 0, stream>>>(s0F, F2C);
        bn_k<<<NN, 256, 0, stream>>>(s0F, g2, be2, 9);
        const float* Sin = s0F;
        for (int it = 0; it < 10; ++it) {
            float* Sout = (it & 1) ? out : R1;
            gemm64_k<float, float><<<dim3(16, 8, 8), 256, 0, stream>>>(
                adj, (size_t)NN * NN, NN, Sin, (size_t)NN * F2C, F2C,
                Sout, (size_t)NN * F2C, NN, F2C, nullptr, s0F, (size_t)NN * F2C, 1, 0, 2);
            Sin = Sout;
        }
        softmax_k<float><<<NB * NN, 256, 0, stream>>>(out, out);
    } else {
        float* Wp0 = ws;
        float* Wp1 = ws + (size_t)NN * F2C;
        float* xW1 = ws;
        float* t1 = out;
        float* h2 = ws;
        float* s0 = out;

        gemm64_k<float, float><<<dim3(128, 2, 1), 256, 0, stream>>>(
            x, 0, F0C, W1, 0, F0C, xW1, 0, F0C, F1C, nullptr, nullptr, 0, 0, 1, 0);
        gemm64_k<float, float><<<dim3(16, 2, 8), 256, 0, stream>>>(
            adj, (size_t)NN * NN, NN, xW1, (size_t)NN * F1C, F1C,
            t1, (size_t)NN * F1C, NN, F1C, b1, nullptr, 0, 0, 0, 1);
        l2relu_k<<<NB * NN, 64, 0, stream>>>(t1, F1C);
        bn_k<<<NN, 256, 0, stream>>>(t1, g1, be1, 7);
        gemm64_k<float, float><<<dim3(16, 2, 8), 256, 0, stream>>>(
            adj, (size_t)NN * NN, NN, t1, (size_t)NN * F1C, F1C,
            h2, (size_t)NN * F1C, NN, F1C, nullptr, nullptr, 0, 0, 0, 0);
        gemm64_k<float, float><<<dim3(128, 8, 1), 256, 0, stream>>>(
            h2, 0, F1C, W2, 0, F1C, s0, 0, F1C, F2C, b2, nullptr, 0, 0, 1, 1);
        l2relu_k<<<NB * NN, 64, 0, stream>>>(s0, F2C);
        bn_k<<<NN, 256, 0, stream>>>(s0, g2, be2, 9);
        for (int b = 0; b < NB; ++b) {
            float* s0b = out + (size_t)b * NN * F2C;
            const float* Ab = adj + (size_t)b * NN * NN;
            const float* Sin = s0b;
            for (int it = 0; it < 10; ++it) {
                float* Sout = (it == 9) ? s0b : ((it & 1) ? Wp1 : Wp0);
                gemm64_k<float, float><<<dim3(16, 8, 1), 256, 0, stream>>>(
                    Ab, 0, NN, Sin, 0, F2C,
                    Sout, 0, NN, F2C, nullptr, s0b, 0, 1, 0, 2);
                Sin = Sout;
            }
        }
        softmax_k<float><<<NB * NN, 256, 0, stream>>>(out, out);
    }
}